// Round 2
// baseline (5066.473 us; speedup 1.0000x reference)
//
#include <hip/hip_runtime.h>

#define N_NODES 50000
#define N_EDGES 800000
#define C_H 128
#define C_OUT 64

// ---------------- degree / norm ----------------
__global__ void init_deg_kernel(float* deg) {
    int i = blockIdx.x * 256 + threadIdx.x;
    if (i < N_NODES) deg[i] = 1.0f;   // self-loop
}

__global__ void deg_scatter_kernel(const int* __restrict__ dst, float* deg) {
    int e = blockIdx.x * 256 + threadIdx.x;
    if (e < N_EDGES) atomicAdd(&deg[dst[e]], 1.0f);
}

__global__ void deg_finalize_kernel(float* deg) {
    int i = blockIdx.x * 256 + threadIdx.x;
    if (i < N_NODES) deg[i] = rsqrtf(deg[i]);   // deg >= 1 always
}

// ---------------- generic matmul: [N, CIN] @ [CIN, COUT] ----------------
// ACT: 0 = none, 1 = relu, 2 = sigmoid
template <int CIN, int COUT, int ACT>
__global__ void mm_kernel(const float* __restrict__ in,
                          const float* __restrict__ W,
                          const float* __restrict__ bias,
                          float* __restrict__ out) {
    int idx = blockIdx.x * 256 + threadIdx.x;
    int row = idx / COUT;
    int c   = idx % COUT;
    if (row >= N_NODES) return;

    float acc = 0.0f;
#pragma unroll 8
    for (int k = 0; k < CIN; ++k) {
        acc = fmaf(in[row * CIN + k], W[k * COUT + c], acc);
    }
    if (bias) acc += bias[c];
    if (ACT == 1) acc = fmaxf(acc, 0.0f);
    if (ACT == 2) acc = 1.0f / (1.0f + expf(-acc));
    out[idx] = acc;
}

// ---------------- edge scatter: agg[dst] += h[src] * norm ----------------
// 32 threads per edge, 4 channels per thread (float4 gather, 4 scalar atomics)
__global__ void edge_scatter_kernel(const int* __restrict__ src,
                                    const int* __restrict__ dst,
                                    const float* __restrict__ dinv,
                                    const float* __restrict__ h,
                                    float* __restrict__ agg) {
    long long idx = (long long)blockIdx.x * 256 + threadIdx.x;
    int e  = (int)(idx >> 5);
    int c4 = ((int)idx & 31) << 2;
    if (e >= N_EDGES) return;
    int s = src[e], d = dst[e];
    float nrm = dinv[s] * dinv[d];
    const float4 hv = *(const float4*)(h + (long long)s * C_H + c4);
    float* ap = agg + (long long)d * C_H + c4;
    atomicAdd(ap + 0, hv.x * nrm);
    atomicAdd(ap + 1, hv.y * nrm);
    atomicAdd(ap + 2, hv.z * nrm);
    atomicAdd(ap + 3, hv.w * nrm);
}

// ---------------- finalize: agg = relu(agg + h*dinv^2 + b) ----------------
__global__ void node_finalize_kernel(const float* __restrict__ h,
                                     const float* __restrict__ dinv,
                                     const float* __restrict__ bias,
                                     float* __restrict__ agg) {
    int idx = blockIdx.x * 256 + threadIdx.x;
    if (idx >= N_NODES * C_H) return;
    int i = idx >> 7;
    int c = idx & 127;
    float di = dinv[i];
    float v = agg[idx] + h[idx] * di * di + bias[c];
    agg[idx] = fmaxf(v, 0.0f);
}

extern "C" void kernel_launch(void* const* d_in, const int* in_sizes, int n_in,
                              void* d_out, int out_size, void* d_ws, size_t ws_size,
                              hipStream_t stream) {
    const float* x   = (const float*)d_in[0];
    const int*   ei  = (const int*)d_in[1];
    const float* W1  = (const float*)d_in[2];
    const float* b1  = (const float*)d_in[3];
    const float* W2  = (const float*)d_in[4];
    const float* b2  = (const float*)d_in[5];
    const float* W3  = (const float*)d_in[6];
    const float* b3  = (const float*)d_in[7];
    const float* Wd1 = (const float*)d_in[8];
    const float* bd1 = (const float*)d_in[9];
    const float* Wd2 = (const float*)d_in[10];
    const float* bd2 = (const float*)d_in[11];

    const int* src = ei;
    const int* dst = ei + N_EDGES;

    // workspace layout (fp32)
    float* dinv = (float*)d_ws;                       // N (rounded to 50176)
    float* bufA = dinv + 50176;                       // N*128
    float* bufB = bufA + (size_t)N_NODES * C_H;       // N*128

    const int nThreads = 256;
    dim3 blk(nThreads);
    dim3 gN((N_NODES + nThreads - 1) / nThreads);
    dim3 gE((N_EDGES + nThreads - 1) / nThreads);
    dim3 gNH(((size_t)N_NODES * C_H + nThreads - 1) / nThreads);
    dim3 gNO(((size_t)N_NODES * C_OUT + nThreads - 1) / nThreads);
    dim3 gScat(((size_t)N_EDGES * 32 + nThreads - 1) / nThreads);

    // degree / norm
    init_deg_kernel<<<gN, blk, 0, stream>>>(dinv);
    deg_scatter_kernel<<<gE, blk, 0, stream>>>(dst, dinv);
    deg_finalize_kernel<<<gN, blk, 0, stream>>>(dinv);

    // ---- GCN layer 1: x -> bufA -> scatter into bufB ----
    mm_kernel<C_H, C_H, 0><<<gNH, blk, 0, stream>>>(x, W1, nullptr, bufA);
    hipMemsetAsync(bufB, 0, (size_t)N_NODES * C_H * sizeof(float), stream);
    edge_scatter_kernel<<<gScat, blk, 0, stream>>>(src, dst, dinv, bufA, bufB);
    node_finalize_kernel<<<gNH, blk, 0, stream>>>(bufA, dinv, b1, bufB);

    // ---- GCN layer 2: bufB -> bufA -> scatter into bufB ----
    mm_kernel<C_H, C_H, 0><<<gNH, blk, 0, stream>>>(bufB, W2, nullptr, bufA);
    hipMemsetAsync(bufB, 0, (size_t)N_NODES * C_H * sizeof(float), stream);
    edge_scatter_kernel<<<gScat, blk, 0, stream>>>(src, dst, dinv, bufA, bufB);
    node_finalize_kernel<<<gNH, blk, 0, stream>>>(bufA, dinv, b2, bufB);

    // ---- GCN layer 3 ----
    mm_kernel<C_H, C_H, 0><<<gNH, blk, 0, stream>>>(bufB, W3, nullptr, bufA);
    hipMemsetAsync(bufB, 0, (size_t)N_NODES * C_H * sizeof(float), stream);
    edge_scatter_kernel<<<gScat, blk, 0, stream>>>(src, dst, dinv, bufA, bufB);
    node_finalize_kernel<<<gNH, blk, 0, stream>>>(bufA, dinv, b3, bufB);

    // ---- dense 1: relu(bufB @ Wd1 + bd1) -> bufA ----
    mm_kernel<C_H, C_H, 1><<<gNH, blk, 0, stream>>>(bufB, Wd1, bd1, bufA);

    // ---- dense 2: sigmoid(bufA @ Wd2 + bd2) -> d_out (fp32) ----
    mm_kernel<C_H, C_OUT, 2><<<gNO, blk, 0, stream>>>(bufA, Wd2, bd2, (float*)d_out);
}

// Round 3
// 928.461 us; speedup vs baseline: 5.4569x; 5.4569x over previous
//
#include <hip/hip_runtime.h>

#define N_NODES 50000
#define N_EDGES 800000
#define C_H 128
#define C_OUT 64

// ================= CSR construction =================

__global__ void hist_kernel(const int* __restrict__ dst, int* __restrict__ counts) {
    int e = blockIdx.x * 256 + threadIdx.x;
    if (e < N_EDGES) atomicAdd(&counts[dst[e]], 1);
}

// dinv[i] = rsqrt(in_degree + 1 self loop)
__global__ void dinv_kernel(const int* __restrict__ counts, float* __restrict__ dinv) {
    int i = blockIdx.x * 256 + threadIdx.x;
    if (i < N_NODES) dinv[i] = rsqrtf((float)counts[i] + 1.0f);
}

// single-block exclusive scan: counts[N] -> rowptr[N+1]
__global__ void __launch_bounds__(1024) scan_kernel(const int* __restrict__ counts,
                                                    int* __restrict__ rowptr) {
    __shared__ int wsum[16];
    __shared__ int carry_s, total_s;
    const int lane = threadIdx.x & 63;
    const int wid  = threadIdx.x >> 6;
    if (threadIdx.x == 0) carry_s = 0;
    __syncthreads();
    for (int base = 0; base < N_NODES; base += 1024) {
        int i = base + (int)threadIdx.x;
        int v = (i < N_NODES) ? counts[i] : 0;
        // wave-inclusive scan (shuffle, no barriers)
        int x = v;
        #pragma unroll
        for (int off = 1; off < 64; off <<= 1) {
            int t = __shfl_up(x, off, 64);
            if (lane >= off) x += t;
        }
        if (lane == 63) wsum[wid] = x;
        __syncthreads();
        if (threadIdx.x == 0) {
            int run = 0;
            #pragma unroll
            for (int w = 0; w < 16; ++w) { int t = wsum[w]; wsum[w] = run; run += t; }
            total_s = run;
        }
        __syncthreads();
        int incl = x + wsum[wid];
        if (i < N_NODES) rowptr[i] = carry_s + incl - v;   // exclusive
        __syncthreads();
        if (threadIdx.x == 0) carry_s += total_s;
        __syncthreads();
    }
    if (threadIdx.x == 0) rowptr[N_NODES] = carry_s;
}

__global__ void copy_rowptr_kernel(const int* __restrict__ rowptr, int* __restrict__ cursor) {
    int i = blockIdx.x * 256 + threadIdx.x;
    if (i < N_NODES) cursor[i] = rowptr[i];
}

__global__ void csr_fill_kernel(const int* __restrict__ src, const int* __restrict__ dst,
                                int* __restrict__ cursor, int* __restrict__ srcs_sorted) {
    int e = blockIdx.x * 256 + threadIdx.x;
    if (e < N_EDGES) {
        int d = dst[e];
        int pos = atomicAdd(&cursor[d], 1);
        srcs_sorted[pos] = src[e];
    }
}

// ================= matmul: out[N,COUT] = act(in[N,CIN] @ W + b) =================
// 4 outputs per thread (float4), ACT: 0=none, 1=relu, 2=sigmoid
template <int CIN, int COUT, int ACT>
__global__ void mm_kernel(const float* __restrict__ in,
                          const float* __restrict__ W,
                          const float* __restrict__ bias,
                          float* __restrict__ out) {
    const int lpr = COUT / 4;   // lanes per row: 32 or 16
    int t   = blockIdx.x * 256 + threadIdx.x;
    int row = t / lpr;
    int c4  = (t % lpr) * 4;
    if (row >= N_NODES) return;

    const float* inr = in + (size_t)row * CIN;
    float4 acc = {0.f, 0.f, 0.f, 0.f};
    #pragma unroll 4
    for (int k = 0; k < CIN; k += 4) {
        float4 a4 = *(const float4*)(inr + k);
        float4 w0 = *(const float4*)(W + (size_t)(k + 0) * COUT + c4);
        float4 w1 = *(const float4*)(W + (size_t)(k + 1) * COUT + c4);
        float4 w2 = *(const float4*)(W + (size_t)(k + 2) * COUT + c4);
        float4 w3 = *(const float4*)(W + (size_t)(k + 3) * COUT + c4);
        acc.x = fmaf(a4.x, w0.x, fmaf(a4.y, w1.x, fmaf(a4.z, w2.x, fmaf(a4.w, w3.x, acc.x))));
        acc.y = fmaf(a4.x, w0.y, fmaf(a4.y, w1.y, fmaf(a4.z, w2.y, fmaf(a4.w, w3.y, acc.y))));
        acc.z = fmaf(a4.x, w0.z, fmaf(a4.y, w1.z, fmaf(a4.z, w2.z, fmaf(a4.w, w3.z, acc.z))));
        acc.w = fmaf(a4.x, w0.w, fmaf(a4.y, w1.w, fmaf(a4.z, w2.w, fmaf(a4.w, w3.w, acc.w))));
    }
    if (bias) {
        float4 b4 = *(const float4*)(bias + c4);
        acc.x += b4.x; acc.y += b4.y; acc.z += b4.z; acc.w += b4.w;
    }
    if (ACT == 1) {
        acc.x = fmaxf(acc.x, 0.f); acc.y = fmaxf(acc.y, 0.f);
        acc.z = fmaxf(acc.z, 0.f); acc.w = fmaxf(acc.w, 0.f);
    }
    if (ACT == 2) {
        acc.x = 1.f / (1.f + expf(-acc.x)); acc.y = 1.f / (1.f + expf(-acc.y));
        acc.z = 1.f / (1.f + expf(-acc.z)); acc.w = 1.f / (1.f + expf(-acc.w));
    }
    *(float4*)(out + (size_t)row * COUT + c4) = acc;
}

// ================= fused gather-aggregate + self-loop + bias + relu =================
// 32 lanes per node, 4 channels per lane (float4). out written exactly once.
__global__ void gather_agg_kernel(const int* __restrict__ rowptr,
                                  const int* __restrict__ srcs,
                                  const float* __restrict__ dinv,
                                  const float* __restrict__ h,
                                  const float* __restrict__ bias,
                                  float* __restrict__ out) {
    int t    = blockIdx.x * 256 + threadIdx.x;
    int node = t >> 5;
    int c4   = (t & 31) << 2;
    if (node >= N_NODES) return;

    float di = dinv[node];
    // self-loop: h[node] * dinv[node]^2
    float4 acc = *(const float4*)(h + (size_t)node * C_H + c4);
    float dii = di * di;
    acc.x *= dii; acc.y *= dii; acc.z *= dii; acc.w *= dii;

    int beg = rowptr[node], end = rowptr[node + 1];
    for (int p = beg; p < end; ++p) {
        int s = srcs[p];
        float nrm = dinv[s] * di;
        float4 hv = *(const float4*)(h + (size_t)s * C_H + c4);
        acc.x = fmaf(hv.x, nrm, acc.x);
        acc.y = fmaf(hv.y, nrm, acc.y);
        acc.z = fmaf(hv.z, nrm, acc.z);
        acc.w = fmaf(hv.w, nrm, acc.w);
    }
    float4 b4 = *(const float4*)(bias + c4);
    acc.x = fmaxf(acc.x + b4.x, 0.f);
    acc.y = fmaxf(acc.y + b4.y, 0.f);
    acc.z = fmaxf(acc.z + b4.z, 0.f);
    acc.w = fmaxf(acc.w + b4.w, 0.f);
    *(float4*)(out + (size_t)node * C_H + c4) = acc;
}

extern "C" void kernel_launch(void* const* d_in, const int* in_sizes, int n_in,
                              void* d_out, int out_size, void* d_ws, size_t ws_size,
                              hipStream_t stream) {
    const float* x   = (const float*)d_in[0];
    const int*   ei  = (const int*)d_in[1];
    const float* W1  = (const float*)d_in[2];
    const float* b1  = (const float*)d_in[3];
    const float* W2  = (const float*)d_in[4];
    const float* b2  = (const float*)d_in[5];
    const float* W3  = (const float*)d_in[6];
    const float* b3  = (const float*)d_in[7];
    const float* Wd1 = (const float*)d_in[8];
    const float* bd1 = (const float*)d_in[9];
    const float* Wd2 = (const float*)d_in[10];
    const float* bd2 = (const float*)d_in[11];

    const int* src = ei;
    const int* dst = ei + N_EDGES;

    // workspace layout (all 16B-aligned offsets)
    float* dinv   = (float*)d_ws;                         // 50176
    float* bufA   = dinv + 50176;                         // 6,400,000
    float* bufB   = bufA + (size_t)N_NODES * C_H;         // 6,400,000
    int*   counts = (int*)(bufB + (size_t)N_NODES * C_H); // 50176
    int*   rowptr = counts + 50176;                       // 50192 (N+1 rounded)
    int*   cursor = rowptr + 50192;                       // 50176
    int*   srcs   = cursor + 50176;                       // 800,000

    const int T = 256;
    dim3 blk(T);
    dim3 gN((N_NODES + T - 1) / T);
    dim3 gE((N_EDGES + T - 1) / T);
    dim3 gMM128(((size_t)N_NODES * 32 + T - 1) / T);
    dim3 gMM64(((size_t)N_NODES * 16 + T - 1) / T);
    dim3 gAgg(((size_t)N_NODES * 32 + T - 1) / T);

    // ---- CSR build + norms ----
    hipMemsetAsync(counts, 0, 50176 * sizeof(int), stream);
    hist_kernel<<<gE, blk, 0, stream>>>(dst, counts);
    dinv_kernel<<<gN, blk, 0, stream>>>(counts, dinv);
    scan_kernel<<<1, 1024, 0, stream>>>(counts, rowptr);
    copy_rowptr_kernel<<<gN, blk, 0, stream>>>(rowptr, cursor);
    csr_fill_kernel<<<gE, blk, 0, stream>>>(src, dst, cursor, srcs);

    // ---- GCN layer 1: x @ W1 -> bufA; aggregate -> bufB ----
    mm_kernel<C_H, C_H, 0><<<gMM128, blk, 0, stream>>>(x, W1, nullptr, bufA);
    gather_agg_kernel<<<gAgg, blk, 0, stream>>>(rowptr, srcs, dinv, bufA, b1, bufB);

    // ---- GCN layer 2 ----
    mm_kernel<C_H, C_H, 0><<<gMM128, blk, 0, stream>>>(bufB, W2, nullptr, bufA);
    gather_agg_kernel<<<gAgg, blk, 0, stream>>>(rowptr, srcs, dinv, bufA, b2, bufB);

    // ---- GCN layer 3 ----
    mm_kernel<C_H, C_H, 0><<<gMM128, blk, 0, stream>>>(bufB, W3, nullptr, bufA);
    gather_agg_kernel<<<gAgg, blk, 0, stream>>>(rowptr, srcs, dinv, bufA, b3, bufB);

    // ---- dense 1: relu(bufB @ Wd1 + bd1) -> bufA ----
    mm_kernel<C_H, C_H, 1><<<gMM128, blk, 0, stream>>>(bufB, Wd1, bd1, bufA);

    // ---- dense 2: sigmoid(bufA @ Wd2 + bd2) -> d_out ----
    mm_kernel<C_H, C_OUT, 2><<<gMM64, blk, 0, stream>>>(bufA, Wd2, bd2, (float*)d_out);
}

// Round 4
// 707.276 us; speedup vs baseline: 7.1634x; 1.3127x over previous
//
#include <hip/hip_runtime.h>

#define N_NODES 50000
#define N_EDGES 800000
#define C_H 128
#define C_OUT 64

// ================= CSR construction =================

__global__ void hist_kernel(const int* __restrict__ dst, int* __restrict__ counts) {
    int e = blockIdx.x * 256 + threadIdx.x;
    if (e < N_EDGES) atomicAdd(&counts[dst[e]], 1);
}

__global__ void dinv_kernel(const int* __restrict__ counts, float* __restrict__ dinv) {
    int i = blockIdx.x * 256 + threadIdx.x;
    if (i < N_NODES) dinv[i] = rsqrtf((float)counts[i] + 1.0f);
}

// single-block exclusive scan: counts[N] -> rowptr[N+1]
__global__ void __launch_bounds__(1024) scan_kernel(const int* __restrict__ counts,
                                                    int* __restrict__ rowptr) {
    __shared__ int wsum[16];
    __shared__ int carry_s, total_s;
    const int lane = threadIdx.x & 63;
    const int wid  = threadIdx.x >> 6;
    if (threadIdx.x == 0) carry_s = 0;
    __syncthreads();
    for (int base = 0; base < N_NODES; base += 1024) {
        int i = base + (int)threadIdx.x;
        int v = (i < N_NODES) ? counts[i] : 0;
        int x = v;
        #pragma unroll
        for (int off = 1; off < 64; off <<= 1) {
            int t = __shfl_up(x, off, 64);
            if (lane >= off) x += t;
        }
        if (lane == 63) wsum[wid] = x;
        __syncthreads();
        if (threadIdx.x == 0) {
            int run = 0;
            #pragma unroll
            for (int w = 0; w < 16; ++w) { int t = wsum[w]; wsum[w] = run; run += t; }
            total_s = run;
        }
        __syncthreads();
        int incl = x + wsum[wid];
        if (i < N_NODES) rowptr[i] = carry_s + incl - v;
        __syncthreads();
        if (threadIdx.x == 0) carry_s += total_s;
        __syncthreads();
    }
    if (threadIdx.x == 0) rowptr[N_NODES] = carry_s;
}

__global__ void copy_rowptr_kernel(const int* __restrict__ rowptr, int* __restrict__ cursor) {
    int i = blockIdx.x * 256 + threadIdx.x;
    if (i < N_NODES) cursor[i] = rowptr[i];
}

__global__ void csr_fill_kernel(const int* __restrict__ src, const int* __restrict__ dst,
                                int* __restrict__ cursor, int* __restrict__ srcs_sorted) {
    int e = blockIdx.x * 256 + threadIdx.x;
    if (e < N_EDGES) {
        int d = dst[e];
        int pos = atomicAdd(&cursor[d], 1);
        srcs_sorted[pos] = src[e];
    }
}

// ================= register-blocked matmul =================
// out[N,COUT] = act(in[N,128] @ W + b). Each thread: R rows x 4 cols.
// ACT: 0=none, 1=relu, 2=sigmoid
template <int COUT, int R, int ACT>
__global__ void __launch_bounds__(256) mm_kernel(const float* __restrict__ in,
                                                 const float* __restrict__ W,
                                                 const float* __restrict__ bias,
                                                 float* __restrict__ out) {
    constexpr int CIN  = 128;
    constexpr int LPR  = COUT / 4;    // lanes across columns (32 or 16)
    constexpr int GRP  = 256 / LPR;   // row groups per block
    constexpr int ROWS = GRP * R;     // rows per block

    const int tx   = threadIdx.x;
    const int c4   = (tx % LPR) * 4;
    const int rg   = tx / LPR;
    const int row0 = blockIdx.x * ROWS + rg * R;

    // clamped row indices for safe loads (duplicates harmless, stores guarded)
    const float* inr[R];
    #pragma unroll
    for (int r = 0; r < R; ++r) {
        int rr = row0 + r;
        if (rr > N_NODES - 1) rr = N_NODES - 1;
        inr[r] = in + (size_t)rr * CIN;
    }

    float4 acc[R];
    #pragma unroll
    for (int r = 0; r < R; ++r) acc[r] = make_float4(0.f, 0.f, 0.f, 0.f);

    #pragma unroll 2
    for (int k = 0; k < CIN; k += 4) {
        float4 w0 = *(const float4*)(W + (size_t)(k + 0) * COUT + c4);
        float4 w1 = *(const float4*)(W + (size_t)(k + 1) * COUT + c4);
        float4 w2 = *(const float4*)(W + (size_t)(k + 2) * COUT + c4);
        float4 w3 = *(const float4*)(W + (size_t)(k + 3) * COUT + c4);
        #pragma unroll
        for (int r = 0; r < R; ++r) {
            float4 a4 = *(const float4*)(inr[r] + k);
            acc[r].x = fmaf(a4.x, w0.x, fmaf(a4.y, w1.x, fmaf(a4.z, w2.x, fmaf(a4.w, w3.x, acc[r].x))));
            acc[r].y = fmaf(a4.x, w0.y, fmaf(a4.y, w1.y, fmaf(a4.z, w2.y, fmaf(a4.w, w3.y, acc[r].y))));
            acc[r].z = fmaf(a4.x, w0.z, fmaf(a4.y, w1.z, fmaf(a4.z, w2.z, fmaf(a4.w, w3.z, acc[r].z))));
            acc[r].w = fmaf(a4.x, w0.w, fmaf(a4.y, w1.w, fmaf(a4.z, w2.w, fmaf(a4.w, w3.w, acc[r].w))));
        }
    }

    float4 b4 = make_float4(0.f, 0.f, 0.f, 0.f);
    if (bias) b4 = *(const float4*)(bias + c4);

    #pragma unroll
    for (int r = 0; r < R; ++r) {
        int rr = row0 + r;
        if (rr >= N_NODES) break;
        float4 v = acc[r];
        v.x += b4.x; v.y += b4.y; v.z += b4.z; v.w += b4.w;
        if (ACT == 1) {
            v.x = fmaxf(v.x, 0.f); v.y = fmaxf(v.y, 0.f);
            v.z = fmaxf(v.z, 0.f); v.w = fmaxf(v.w, 0.f);
        }
        if (ACT == 2) {
            v.x = 1.f / (1.f + expf(-v.x)); v.y = 1.f / (1.f + expf(-v.y));
            v.z = 1.f / (1.f + expf(-v.z)); v.w = 1.f / (1.f + expf(-v.w));
        }
        *(float4*)(out + (size_t)rr * COUT + c4) = v;
    }
}

// ================= fused gather-aggregate + self-loop + bias + relu =================
__global__ void gather_agg_kernel(const int* __restrict__ rowptr,
                                  const int* __restrict__ srcs,
                                  const float* __restrict__ dinv,
                                  const float* __restrict__ h,
                                  const float* __restrict__ bias,
                                  float* __restrict__ out) {
    int t    = blockIdx.x * 256 + threadIdx.x;
    int node = t >> 5;
    int c4   = (t & 31) << 2;
    if (node >= N_NODES) return;

    float di = dinv[node];
    float4 acc = *(const float4*)(h + (size_t)node * C_H + c4);
    float dii = di * di;
    acc.x *= dii; acc.y *= dii; acc.z *= dii; acc.w *= dii;

    int beg = rowptr[node], end = rowptr[node + 1];
    for (int p = beg; p < end; ++p) {
        int s = srcs[p];
        float nrm = dinv[s] * di;
        float4 hv = *(const float4*)(h + (size_t)s * C_H + c4);
        acc.x = fmaf(hv.x, nrm, acc.x);
        acc.y = fmaf(hv.y, nrm, acc.y);
        acc.z = fmaf(hv.z, nrm, acc.z);
        acc.w = fmaf(hv.w, nrm, acc.w);
    }
    float4 b4 = *(const float4*)(bias + c4);
    acc.x = fmaxf(acc.x + b4.x, 0.f);
    acc.y = fmaxf(acc.y + b4.y, 0.f);
    acc.z = fmaxf(acc.z + b4.z, 0.f);
    acc.w = fmaxf(acc.w + b4.w, 0.f);
    *(float4*)(out + (size_t)node * C_H + c4) = acc;
}

extern "C" void kernel_launch(void* const* d_in, const int* in_sizes, int n_in,
                              void* d_out, int out_size, void* d_ws, size_t ws_size,
                              hipStream_t stream) {
    const float* x   = (const float*)d_in[0];
    const int*   ei  = (const int*)d_in[1];
    const float* W1  = (const float*)d_in[2];
    const float* b1  = (const float*)d_in[3];
    const float* W2  = (const float*)d_in[4];
    const float* b2  = (const float*)d_in[5];
    const float* W3  = (const float*)d_in[6];
    const float* b3  = (const float*)d_in[7];
    const float* Wd1 = (const float*)d_in[8];
    const float* bd1 = (const float*)d_in[9];
    const float* Wd2 = (const float*)d_in[10];
    const float* bd2 = (const float*)d_in[11];

    const int* src = ei;
    const int* dst = ei + N_EDGES;

    float* dinv   = (float*)d_ws;                         // 50176
    float* bufA   = dinv + 50176;                         // 6,400,000
    float* bufB   = bufA + (size_t)N_NODES * C_H;         // 6,400,000
    int*   counts = (int*)(bufB + (size_t)N_NODES * C_H); // 50176
    int*   rowptr = counts + 50176;                       // 50192
    int*   cursor = rowptr + 50192;                       // 50176
    int*   srcs   = cursor + 50176;                       // 800,000

    const int T = 256;
    dim3 blk(T);
    dim3 gN((N_NODES + T - 1) / T);
    dim3 gE((N_EDGES + T - 1) / T);
    dim3 gAgg(((size_t)N_NODES * 32 + T - 1) / T);

    // mm grids: COUT=128,R=8 -> 64 rows/block; COUT=64,R=8 -> 128 rows/block
    dim3 gMM128((N_NODES + 63) / 64);
    dim3 gMM64((N_NODES + 127) / 128);

    // ---- CSR build + norms ----
    hipMemsetAsync(counts, 0, 50176 * sizeof(int), stream);
    hist_kernel<<<gE, blk, 0, stream>>>(dst, counts);
    dinv_kernel<<<gN, blk, 0, stream>>>(counts, dinv);
    scan_kernel<<<1, 1024, 0, stream>>>(counts, rowptr);
    copy_rowptr_kernel<<<gN, blk, 0, stream>>>(rowptr, cursor);
    csr_fill_kernel<<<gE, blk, 0, stream>>>(src, dst, cursor, srcs);

    // ---- GCN layer 1 ----
    mm_kernel<C_H, 8, 0><<<gMM128, blk, 0, stream>>>(x, W1, nullptr, bufA);
    gather_agg_kernel<<<gAgg, blk, 0, stream>>>(rowptr, srcs, dinv, bufA, b1, bufB);

    // ---- GCN layer 2 ----
    mm_kernel<C_H, 8, 0><<<gMM128, blk, 0, stream>>>(bufB, W2, nullptr, bufA);
    gather_agg_kernel<<<gAgg, blk, 0, stream>>>(rowptr, srcs, dinv, bufA, b2, bufB);

    // ---- GCN layer 3 ----
    mm_kernel<C_H, 8, 0><<<gMM128, blk, 0, stream>>>(bufB, W3, nullptr, bufA);
    gather_agg_kernel<<<gAgg, blk, 0, stream>>>(rowptr, srcs, dinv, bufA, b3, bufB);

    // ---- dense 1 ----
    mm_kernel<C_H, 8, 1><<<gMM128, blk, 0, stream>>>(bufB, Wd1, bd1, bufA);

    // ---- dense 2 ----
    mm_kernel<C_OUT, 8, 2><<<gMM64, blk, 0, stream>>>(bufA, Wd2, bd2, (float*)d_out);
}

// Round 5
// 595.899 us; speedup vs baseline: 8.5022x; 1.1869x over previous
//
#include <hip/hip_runtime.h>

#define N_NODES 50000
#define N_EDGES 800000
#define C_H 128
#define C_OUT 64

// ================= CSR construction =================

__global__ void hist_kernel(const int* __restrict__ dst, int* __restrict__ counts) {
    int e = blockIdx.x * 256 + threadIdx.x;
    if (e < N_EDGES) atomicAdd(&counts[dst[e]], 1);
}

__global__ void dinv_kernel(const int* __restrict__ counts, float* __restrict__ dinv) {
    int i = blockIdx.x * 256 + threadIdx.x;
    if (i < N_NODES) dinv[i] = rsqrtf((float)counts[i] + 1.0f);
}

// single-block exclusive scan: counts[N] -> rowptr[N+1]
__global__ void __launch_bounds__(1024) scan_kernel(const int* __restrict__ counts,
                                                    int* __restrict__ rowptr) {
    __shared__ int wsum[16];
    __shared__ int carry_s, total_s;
    const int lane = threadIdx.x & 63;
    const int wid  = threadIdx.x >> 6;
    if (threadIdx.x == 0) carry_s = 0;
    __syncthreads();
    for (int base = 0; base < N_NODES; base += 1024) {
        int i = base + (int)threadIdx.x;
        int v = (i < N_NODES) ? counts[i] : 0;
        int x = v;
        #pragma unroll
        for (int off = 1; off < 64; off <<= 1) {
            int t = __shfl_up(x, off, 64);
            if (lane >= off) x += t;
        }
        if (lane == 63) wsum[wid] = x;
        __syncthreads();
        if (threadIdx.x == 0) {
            int run = 0;
            #pragma unroll
            for (int w = 0; w < 16; ++w) { int t = wsum[w]; wsum[w] = run; run += t; }
            total_s = run;
        }
        __syncthreads();
        int incl = x + wsum[wid];
        if (i < N_NODES) rowptr[i] = carry_s + incl - v;
        __syncthreads();
        if (threadIdx.x == 0) carry_s += total_s;
        __syncthreads();
    }
    if (threadIdx.x == 0) rowptr[N_NODES] = carry_s;
}

__global__ void copy_rowptr_kernel(const int* __restrict__ rowptr, int* __restrict__ cursor) {
    int i = blockIdx.x * 256 + threadIdx.x;
    if (i < N_NODES) cursor[i] = rowptr[i];
}

__global__ void csr_fill_kernel(const int* __restrict__ src, const int* __restrict__ dst,
                                int* __restrict__ cursor, int* __restrict__ srcs_sorted) {
    int e = blockIdx.x * 256 + threadIdx.x;
    if (e < N_EDGES) {
        int d = dst[e];
        int pos = atomicAdd(&cursor[d], 1);
        srcs_sorted[pos] = src[e];
    }
}

// ================= register-blocked matmul, W staged in LDS =================
// out[N,COUT] = act(in[N,128] @ W + b). Each thread: R rows x 4 cols.
// ACT: 0=none, 1=relu, 2=sigmoid
template <int COUT, int R, int ACT>
__global__ void __launch_bounds__(256) mm_kernel(const float* __restrict__ in,
                                                 const float* __restrict__ W,
                                                 const float* __restrict__ bias,
                                                 float* __restrict__ out) {
    constexpr int CIN  = 128;
    constexpr int LPR  = COUT / 4;    // lanes across columns (32 or 16)
    constexpr int GRP  = 256 / LPR;   // row groups per block
    constexpr int ROWS = GRP * R;     // rows per block
    constexpr int WN4  = CIN * COUT / 4;   // W size in float4

    __shared__ float sW[CIN * COUT];

    // ---- stage W into LDS (coalesced float4) ----
    {
        float4*       s4 = (float4*)sW;
        const float4* w4 = (const float4*)W;
        #pragma unroll
        for (int i = 0; i < WN4 / 256; ++i)
            s4[threadIdx.x + i * 256] = w4[threadIdx.x + i * 256];
    }
    __syncthreads();

    const int tx   = threadIdx.x;
    const int c4   = (tx % LPR) * 4;
    const int rg   = tx / LPR;
    const int row0 = blockIdx.x * ROWS + rg * R;

    const float* inr[R];
    #pragma unroll
    for (int r = 0; r < R; ++r) {
        int rr = row0 + r;
        if (rr > N_NODES - 1) rr = N_NODES - 1;
        inr[r] = in + (size_t)rr * CIN;
    }

    float4 acc[R];
    #pragma unroll
    for (int r = 0; r < R; ++r) acc[r] = make_float4(0.f, 0.f, 0.f, 0.f);

    #pragma unroll 2
    for (int k = 0; k < CIN; k += 4) {
        float4 w0 = *(const float4*)(sW + (k + 0) * COUT + c4);
        float4 w1 = *(const float4*)(sW + (k + 1) * COUT + c4);
        float4 w2 = *(const float4*)(sW + (k + 2) * COUT + c4);
        float4 w3 = *(const float4*)(sW + (k + 3) * COUT + c4);
        #pragma unroll
        for (int r = 0; r < R; ++r) {
            float4 a4 = *(const float4*)(inr[r] + k);
            acc[r].x = fmaf(a4.x, w0.x, fmaf(a4.y, w1.x, fmaf(a4.z, w2.x, fmaf(a4.w, w3.x, acc[r].x))));
            acc[r].y = fmaf(a4.x, w0.y, fmaf(a4.y, w1.y, fmaf(a4.z, w2.y, fmaf(a4.w, w3.y, acc[r].y))));
            acc[r].z = fmaf(a4.x, w0.z, fmaf(a4.y, w1.z, fmaf(a4.z, w2.z, fmaf(a4.w, w3.z, acc[r].z))));
            acc[r].w = fmaf(a4.x, w0.w, fmaf(a4.y, w1.w, fmaf(a4.z, w2.w, fmaf(a4.w, w3.w, acc[r].w))));
        }
    }

    float4 b4 = make_float4(0.f, 0.f, 0.f, 0.f);
    if (bias) b4 = *(const float4*)(bias + c4);

    #pragma unroll
    for (int r = 0; r < R; ++r) {
        int rr = row0 + r;
        if (rr >= N_NODES) break;
        float4 v = acc[r];
        v.x += b4.x; v.y += b4.y; v.z += b4.z; v.w += b4.w;
        if (ACT == 1) {
            v.x = fmaxf(v.x, 0.f); v.y = fmaxf(v.y, 0.f);
            v.z = fmaxf(v.z, 0.f); v.w = fmaxf(v.w, 0.f);
        }
        if (ACT == 2) {
            v.x = 1.f / (1.f + expf(-v.x)); v.y = 1.f / (1.f + expf(-v.y));
            v.z = 1.f / (1.f + expf(-v.z)); v.w = 1.f / (1.f + expf(-v.w));
        }
        *(float4*)(out + (size_t)rr * COUT + c4) = v;
    }
}

// ================= fused gather-aggregate + self-loop + bias + relu =================
__global__ void gather_agg_kernel(const int* __restrict__ rowptr,
                                  const int* __restrict__ srcs,
                                  const float* __restrict__ dinv,
                                  const float* __restrict__ h,
                                  const float* __restrict__ bias,
                                  float* __restrict__ out) {
    int t    = blockIdx.x * 256 + threadIdx.x;
    int node = t >> 5;
    int c4   = (t & 31) << 2;
    if (node >= N_NODES) return;

    float di = dinv[node];
    float4 acc = *(const float4*)(h + (size_t)node * C_H + c4);
    float dii = di * di;
    acc.x *= dii; acc.y *= dii; acc.z *= dii; acc.w *= dii;

    int beg = rowptr[node], end = rowptr[node + 1];
    for (int p = beg; p < end; ++p) {
        int s = srcs[p];
        float nrm = dinv[s] * di;
        float4 hv = *(const float4*)(h + (size_t)s * C_H + c4);
        acc.x = fmaf(hv.x, nrm, acc.x);
        acc.y = fmaf(hv.y, nrm, acc.y);
        acc.z = fmaf(hv.z, nrm, acc.z);
        acc.w = fmaf(hv.w, nrm, acc.w);
    }
    float4 b4 = *(const float4*)(bias + c4);
    acc.x = fmaxf(acc.x + b4.x, 0.f);
    acc.y = fmaxf(acc.y + b4.y, 0.f);
    acc.z = fmaxf(acc.z + b4.z, 0.f);
    acc.w = fmaxf(acc.w + b4.w, 0.f);
    *(float4*)(out + (size_t)node * C_H + c4) = acc;
}

extern "C" void kernel_launch(void* const* d_in, const int* in_sizes, int n_in,
                              void* d_out, int out_size, void* d_ws, size_t ws_size,
                              hipStream_t stream) {
    const float* x   = (const float*)d_in[0];
    const int*   ei  = (const int*)d_in[1];
    const float* W1  = (const float*)d_in[2];
    const float* b1  = (const float*)d_in[3];
    const float* W2  = (const float*)d_in[4];
    const float* b2  = (const float*)d_in[5];
    const float* W3  = (const float*)d_in[6];
    const float* b3  = (const float*)d_in[7];
    const float* Wd1 = (const float*)d_in[8];
    const float* bd1 = (const float*)d_in[9];
    const float* Wd2 = (const float*)d_in[10];
    const float* bd2 = (const float*)d_in[11];

    const int* src = ei;
    const int* dst = ei + N_EDGES;

    float* dinv   = (float*)d_ws;                         // 50176
    float* bufA   = dinv + 50176;                         // 6,400,000
    float* bufB   = bufA + (size_t)N_NODES * C_H;         // 6,400,000
    int*   counts = (int*)(bufB + (size_t)N_NODES * C_H); // 50176
    int*   rowptr = counts + 50176;                       // 50192
    int*   cursor = rowptr + 50192;                       // 50176
    int*   srcs   = cursor + 50176;                       // 800,000

    const int T = 256;
    dim3 blk(T);
    dim3 gN((N_NODES + T - 1) / T);
    dim3 gE((N_EDGES + T - 1) / T);
    dim3 gAgg(((size_t)N_NODES * 32 + T - 1) / T);

    // mm grids: COUT=128,R=8 -> 64 rows/block; COUT=64,R=8 -> 128 rows/block
    dim3 gMM128((N_NODES + 63) / 64);
    dim3 gMM64((N_NODES + 127) / 128);

    // ---- CSR build + norms ----
    hipMemsetAsync(counts, 0, 50176 * sizeof(int), stream);
    hist_kernel<<<gE, blk, 0, stream>>>(dst, counts);
    dinv_kernel<<<gN, blk, 0, stream>>>(counts, dinv);
    scan_kernel<<<1, 1024, 0, stream>>>(counts, rowptr);
    copy_rowptr_kernel<<<gN, blk, 0, stream>>>(rowptr, cursor);
    csr_fill_kernel<<<gE, blk, 0, stream>>>(src, dst, cursor, srcs);

    // ---- GCN layer 1 ----
    mm_kernel<C_H, 8, 0><<<gMM128, blk, 0, stream>>>(x, W1, nullptr, bufA);
    gather_agg_kernel<<<gAgg, blk, 0, stream>>>(rowptr, srcs, dinv, bufA, b1, bufB);

    // ---- GCN layer 2 ----
    mm_kernel<C_H, 8, 0><<<gMM128, blk, 0, stream>>>(bufB, W2, nullptr, bufA);
    gather_agg_kernel<<<gAgg, blk, 0, stream>>>(rowptr, srcs, dinv, bufA, b2, bufB);

    // ---- GCN layer 3 ----
    mm_kernel<C_H, 8, 0><<<gMM128, blk, 0, stream>>>(bufB, W3, nullptr, bufA);
    gather_agg_kernel<<<gAgg, blk, 0, stream>>>(rowptr, srcs, dinv, bufA, b3, bufB);

    // ---- dense 1 ----
    mm_kernel<C_H, 8, 1><<<gMM128, blk, 0, stream>>>(bufB, Wd1, bd1, bufA);

    // ---- dense 2 ----
    mm_kernel<C_OUT, 8, 2><<<gMM64, blk, 0, stream>>>(bufA, Wd2, bd2, (float*)d_out);
}

// Round 6
// 382.718 us; speedup vs baseline: 13.2381x; 1.5570x over previous
//
#include <hip/hip_runtime.h>
#include <hip/hip_bf16.h>

#define N_NODES 50000
#define N_EDGES 800000
#define C_H 128
#define C_OUT 64
#define NBLK 196          // ceil(50000/256)

typedef __attribute__((ext_vector_type(8))) short bf16x8;
typedef __attribute__((ext_vector_type(4))) float f32x4;

static __device__ __forceinline__ float bf_lo(unsigned int u) { return __uint_as_float(u << 16); }
static __device__ __forceinline__ float bf_hi(unsigned int u) { return __uint_as_float(u & 0xffff0000u); }
static __device__ __forceinline__ unsigned short f2bf(float f) {
    __hip_bfloat16 h = __float2bfloat16(f);
    return *(unsigned short*)&h;
}
static __device__ __forceinline__ unsigned int pack2(float a, float b) {
    return (unsigned int)f2bf(a) | ((unsigned int)f2bf(b) << 16);
}

// ================= CSR construction =================

__global__ void hist_kernel(const int* __restrict__ dst, int* __restrict__ counts) {
    int e = blockIdx.x * 256 + threadIdx.x;
    if (e < N_EDGES) atomicAdd(&counts[dst[e]], 1);
}

__global__ void dinv_kernel(const int* __restrict__ counts, float* __restrict__ dinv) {
    int i = blockIdx.x * 256 + threadIdx.x;
    if (i < N_NODES) dinv[i] = rsqrtf((float)counts[i] + 1.0f);
}

// hierarchical scan, phase 1: per-block exclusive scan + block sums
__global__ void __launch_bounds__(256) scan1_kernel(const int* __restrict__ counts,
                                                    int* __restrict__ eblk,
                                                    int* __restrict__ bsum) {
    __shared__ int ws[4];
    int i = blockIdx.x * 256 + threadIdx.x;
    int v = (i < N_NODES) ? counts[i] : 0;
    int lane = threadIdx.x & 63, w = threadIdx.x >> 6;
    int x = v;
    #pragma unroll
    for (int off = 1; off < 64; off <<= 1) {
        int t = __shfl_up(x, off, 64);
        if (lane >= off) x += t;
    }
    if (lane == 63) ws[w] = x;
    __syncthreads();
    if (threadIdx.x == 0) {
        int run = 0;
        #pragma unroll
        for (int k = 0; k < 4; ++k) { int t = ws[k]; ws[k] = run; run += t; }
        bsum[blockIdx.x] = run;
    }
    __syncthreads();
    if (i < N_NODES) eblk[i] = x - v + ws[w];
}

// phase 2: single block scans NBLK block sums -> block offsets; writes rowptr[N]
__global__ void __launch_bounds__(256) scan2_kernel(const int* __restrict__ bsum,
                                                    int* __restrict__ bo,
                                                    int* __restrict__ rowptr) {
    __shared__ int ws[4];
    int i = threadIdx.x;
    int v = (i < NBLK) ? bsum[i] : 0;
    int lane = i & 63, w = i >> 6;
    int x = v;
    #pragma unroll
    for (int off = 1; off < 64; off <<= 1) {
        int t = __shfl_up(x, off, 64);
        if (lane >= off) x += t;
    }
    if (lane == 63) ws[w] = x;
    __syncthreads();
    if (i == 0) {
        int run = 0;
        #pragma unroll
        for (int k = 0; k < 4; ++k) { int t = ws[k]; ws[k] = run; run += t; }
    }
    __syncthreads();
    int excl = x - v + ws[w];
    if (i < NBLK) bo[i] = excl;
    if (i == 255) rowptr[N_NODES] = excl + v;   // v=0 here -> total
}

// phase 3: rowptr = eblk + bo[block]; also init cursor
__global__ void scan3_kernel(const int* __restrict__ eblk, const int* __restrict__ bo,
                             int* __restrict__ rowptr, int* __restrict__ cursor) {
    int i = blockIdx.x * 256 + threadIdx.x;
    if (i < N_NODES) {
        int r = eblk[i] + bo[blockIdx.x];
        rowptr[i] = r;
        cursor[i] = r;
    }
}

__global__ void csr_fill_kernel(const int* __restrict__ src, const int* __restrict__ dst,
                                const float* __restrict__ dinv,
                                int* __restrict__ cursor,
                                int* __restrict__ srcs, float* __restrict__ enorm) {
    int e = blockIdx.x * 256 + threadIdx.x;
    if (e < N_EDGES) {
        int d = dst[e], s = src[e];
        int pos = atomicAdd(&cursor[d], 1);
        srcs[pos]  = s;
        enorm[pos] = dinv[s] * dinv[d];
    }
}

// ================= fp32 -> bf16 convert (x), 4 elems/thread =================
__global__ void cvt_bf16_kernel(const float* __restrict__ in, unsigned short* __restrict__ out) {
    int i = blockIdx.x * 256 + threadIdx.x;          // over (N*C_H)/4
    if (i >= N_NODES * C_H / 4) return;
    float4 v = *(const float4*)(in + (size_t)i * 4);
    ushort4 u;
    u.x = f2bf(v.x); u.y = f2bf(v.y); u.z = f2bf(v.z); u.w = f2bf(v.w);
    *(ushort4*)(out + (size_t)i * 4) = u;
}

// ================= W packing into MFMA fragment order =================
// packed[(((kb*NB)+nb)*64 + lane)*8 + j] = W[kb*32 + (lane>>4)*8 + j][nb*16 + (lane&15)]
template <int COUT>
__global__ void pack_w_kernel(const float* __restrict__ W, unsigned short* __restrict__ P) {
    constexpr int NB = COUT / 16;
    int idx = blockIdx.x * 256 + threadIdx.x;
    if (idx >= 128 * COUT) return;
    int j    = idx & 7;
    int lane = (idx >> 3) & 63;
    int t    = idx >> 9;               // kb*NB + nb
    int nb = t % NB, kb = t / NB;
    int k = kb * 32 + ((lane >> 4) << 3) + j;
    int n = nb * 16 + (lane & 15);
    P[idx] = f2bf(W[(size_t)k * COUT + n]);
}

// ================= MFMA matmul =================
// out = act(in @ W + b); in bf16 [N,128]; one wave -> 16 rows x COUT.
// OUT_MODE: 0 = bf16, no bias/act; 1 = bf16, bias+relu; 2 = fp32, bias+sigmoid
template <int COUT, int OUT_MODE>
__global__ void __launch_bounds__(256) mm_mfma_kernel(
        const unsigned short* __restrict__ hin,
        const unsigned short* __restrict__ Wp,
        const float* __restrict__ bias,
        unsigned short* __restrict__ out_b,
        float* __restrict__ out_f) {
    constexpr int NB = COUT / 16;
    const int lane = threadIdx.x & 63;
    const int wave = threadIdx.x >> 6;
    const int wid  = blockIdx.x * 4 + wave;
    if (wid * 16 >= N_NODES) return;
    const int node = wid * 16 + (lane & 15);
    const int quad = lane >> 4;

    f32x4 acc[NB];
    #pragma unroll
    for (int nb = 0; nb < NB; ++nb) acc[nb] = (f32x4){0.f, 0.f, 0.f, 0.f};

    #pragma unroll
    for (int kb = 0; kb < 4; ++kb) {
        bf16x8 hf = *(const bf16x8*)(hin + (size_t)node * 128 + kb * 32 + quad * 8);
        #pragma unroll
        for (int nb = 0; nb < NB; ++nb) {
            bf16x8 wf = *(const bf16x8*)(Wp + ((size_t)(kb * NB + nb) * 64 + lane) * 8);
            // D[n][m] = sum_k W[k][n]*H[m][k]: pass W-frag as A, h-frag as B.
            // C/D: col(lane&15)=node row, "row"(quad*4+r)=channel -> 4 consecutive channels/lane.
            acc[nb] = __builtin_amdgcn_mfma_f32_16x16x32_bf16(wf, hf, acc[nb], 0, 0, 0);
        }
    }

    #pragma unroll
    for (int nb = 0; nb < NB; ++nb) {
        int ch = nb * 16 + quad * 4;
        float vx = acc[nb][0], vy = acc[nb][1], vz = acc[nb][2], vw = acc[nb][3];
        if (OUT_MODE >= 1) {
            float4 b4 = *(const float4*)(bias + ch);
            vx += b4.x; vy += b4.y; vz += b4.z; vw += b4.w;
        }
        if (OUT_MODE == 1) {
            vx = fmaxf(vx, 0.f); vy = fmaxf(vy, 0.f);
            vz = fmaxf(vz, 0.f); vw = fmaxf(vw, 0.f);
        }
        if (OUT_MODE == 2) {
            vx = 1.f / (1.f + expf(-vx)); vy = 1.f / (1.f + expf(-vy));
            vz = 1.f / (1.f + expf(-vz)); vw = 1.f / (1.f + expf(-vw));
            *(float4*)(out_f + (size_t)node * COUT + ch) = make_float4(vx, vy, vz, vw);
        } else {
            uint2 o;
            o.x = pack2(vx, vy);
            o.y = pack2(vz, vw);
            *(uint2*)(out_b + (size_t)node * COUT + ch) = o;
        }
    }
}

// ================= fused gather-aggregate (bf16 in/out) =================
// 16 lanes per node, 8 channels per lane. out = relu(sum + selfloop + bias), bf16.
__global__ void __launch_bounds__(256) gather_agg_kernel(
        const int* __restrict__ rowptr,
        const int* __restrict__ srcs,
        const float* __restrict__ enorm,
        const float* __restrict__ dinv,
        const unsigned short* __restrict__ h,
        const float* __restrict__ bias,
        unsigned short* __restrict__ out) {
    int t    = blockIdx.x * 256 + threadIdx.x;
    int node = t >> 4;
    int c8   = (t & 15) << 3;
    if (node >= N_NODES) return;

    float di = dinv[node];
    float dii = di * di;
    uint4 raw = *(const uint4*)(h + (size_t)node * C_H + c8);
    float a0 = bf_lo(raw.x) * dii, a1 = bf_hi(raw.x) * dii;
    float a2 = bf_lo(raw.y) * dii, a3 = bf_hi(raw.y) * dii;
    float a4 = bf_lo(raw.z) * dii, a5 = bf_hi(raw.z) * dii;
    float a6 = bf_lo(raw.w) * dii, a7 = bf_hi(raw.w) * dii;

    int beg = rowptr[node], end = rowptr[node + 1];
    for (int p = beg; p < end; ++p) {
        int s = srcs[p];
        float nrm = enorm[p];
        uint4 rv = *(const uint4*)(h + (size_t)s * C_H + c8);
        a0 = fmaf(bf_lo(rv.x), nrm, a0); a1 = fmaf(bf_hi(rv.x), nrm, a1);
        a2 = fmaf(bf_lo(rv.y), nrm, a2); a3 = fmaf(bf_hi(rv.y), nrm, a3);
        a4 = fmaf(bf_lo(rv.z), nrm, a4); a5 = fmaf(bf_hi(rv.z), nrm, a5);
        a6 = fmaf(bf_lo(rv.w), nrm, a6); a7 = fmaf(bf_hi(rv.w), nrm, a7);
    }

    float4 ba = *(const float4*)(bias + c8);
    float4 bb = *(const float4*)(bias + c8 + 4);
    a0 = fmaxf(a0 + ba.x, 0.f); a1 = fmaxf(a1 + ba.y, 0.f);
    a2 = fmaxf(a2 + ba.z, 0.f); a3 = fmaxf(a3 + ba.w, 0.f);
    a4 = fmaxf(a4 + bb.x, 0.f); a5 = fmaxf(a5 + bb.y, 0.f);
    a6 = fmaxf(a6 + bb.z, 0.f); a7 = fmaxf(a7 + bb.w, 0.f);

    uint4 o;
    o.x = pack2(a0, a1); o.y = pack2(a2, a3);
    o.z = pack2(a4, a5); o.w = pack2(a6, a7);
    *(uint4*)(out + (size_t)node * C_H + c8) = o;
}

extern "C" void kernel_launch(void* const* d_in, const int* in_sizes, int n_in,
                              void* d_out, int out_size, void* d_ws, size_t ws_size,
                              hipStream_t stream) {
    const float* x   = (const float*)d_in[0];
    const int*   ei  = (const int*)d_in[1];
    const float* W1  = (const float*)d_in[2];
    const float* b1  = (const float*)d_in[3];
    const float* W2  = (const float*)d_in[4];
    const float* b2  = (const float*)d_in[5];
    const float* W3  = (const float*)d_in[6];
    const float* b3  = (const float*)d_in[7];
    const float* Wd1 = (const float*)d_in[8];
    const float* bd1 = (const float*)d_in[9];
    const float* Wd2 = (const float*)d_in[10];
    const float* bd2 = (const float*)d_in[11];

    const int* src = ei;
    const int* dst = ei + N_EDGES;

    // ---- workspace layout (byte offsets, 256-aligned) ----
    char* base = (char*)d_ws;
    size_t off = 0;
    auto alloc = [&](size_t bytes) { char* p = base + off; off += (bytes + 255) & ~size_t(255); return p; };
    float*          dinv   = (float*)alloc(N_NODES * 4);
    int*            counts = (int*)alloc(N_NODES * 4);
    int*            rowptr = (int*)alloc((N_NODES + 1) * 4);
    int*            cursor = (int*)alloc(N_NODES * 4);
    int*            eblk   = (int*)alloc(N_NODES * 4);
    int*            bsum   = (int*)alloc(256 * 4);
    int*            bo     = (int*)alloc(256 * 4);
    int*            srcs   = (int*)alloc(N_EDGES * 4);
    float*          enorm  = (float*)alloc(N_EDGES * 4);
    unsigned short* xb     = (unsigned short*)alloc((size_t)N_NODES * C_H * 2);
    unsigned short* bufA   = (unsigned short*)alloc((size_t)N_NODES * C_H * 2);
    unsigned short* bufB   = (unsigned short*)alloc((size_t)N_NODES * C_H * 2);
    unsigned short* P1     = (unsigned short*)alloc(128 * 128 * 2);
    unsigned short* P2     = (unsigned short*)alloc(128 * 128 * 2);
    unsigned short* P3     = (unsigned short*)alloc(128 * 128 * 2);
    unsigned short* Pd1    = (unsigned short*)alloc(128 * 128 * 2);
    unsigned short* Pd2    = (unsigned short*)alloc(128 * 64 * 2);

    const int T = 256;
    dim3 blk(T);
    dim3 gN((N_NODES + T - 1) / T);          // 196
    dim3 gE((N_EDGES + T - 1) / T);
    dim3 gCvt((N_NODES * C_H / 4 + T - 1) / T);
    dim3 gMM((N_NODES / 16 + 3) / 4);        // 782 blocks, 4 waves each
    dim3 gAgg((N_NODES * 16 + T - 1) / T);   // 3125
    dim3 gPak128((128 * 128 + T - 1) / T);
    dim3 gPak64((128 * 64 + T - 1) / T);

    // ---- CSR + norms ----
    hipMemsetAsync(counts, 0, N_NODES * 4, stream);
    hist_kernel<<<gE, blk, 0, stream>>>(dst, counts);
    dinv_kernel<<<gN, blk, 0, stream>>>(counts, dinv);
    scan1_kernel<<<gN, blk, 0, stream>>>(counts, eblk, bsum);
    scan2_kernel<<<1, blk, 0, stream>>>(bsum, bo, rowptr);
    scan3_kernel<<<gN, blk, 0, stream>>>(eblk, bo, rowptr, cursor);
    csr_fill_kernel<<<gE, blk, 0, stream>>>(src, dst, dinv, cursor, srcs, enorm);

    // ---- input convert + weight packing ----
    cvt_bf16_kernel<<<gCvt, blk, 0, stream>>>(x, xb);
    pack_w_kernel<128><<<gPak128, blk, 0, stream>>>(W1, P1);
    pack_w_kernel<128><<<gPak128, blk, 0, stream>>>(W2, P2);
    pack_w_kernel<128><<<gPak128, blk, 0, stream>>>(W3, P3);
    pack_w_kernel<128><<<gPak128, blk, 0, stream>>>(Wd1, Pd1);
    pack_w_kernel<64><<<gPak64, blk, 0, stream>>>(Wd2, Pd2);

    // ---- GCN layer 1 ----
    mm_mfma_kernel<128, 0><<<gMM, blk, 0, stream>>>(xb, P1, nullptr, bufA, nullptr);
    gather_agg_kernel<<<gAgg, blk, 0, stream>>>(rowptr, srcs, enorm, dinv, bufA, b1, bufB);
    // ---- GCN layer 2 ----
    mm_mfma_kernel<128, 0><<<gMM, blk, 0, stream>>>(bufB, P2, nullptr, bufA, nullptr);
    gather_agg_kernel<<<gAgg, blk, 0, stream>>>(rowptr, srcs, enorm, dinv, bufA, b2, bufB);
    // ---- GCN layer 3 ----
    mm_mfma_kernel<128, 0><<<gMM, blk, 0, stream>>>(bufB, P3, nullptr, bufA, nullptr);
    gather_agg_kernel<<<gAgg, blk, 0, stream>>>(rowptr, srcs, enorm, dinv, bufA, b3, bufB);

    // ---- dense 1: relu(bufB @ Wd1 + bd1) -> bufA (bf16) ----
    mm_mfma_kernel<128, 1><<<gMM, blk, 0, stream>>>(bufB, Pd1, bd1, bufA, nullptr);
    // ---- dense 2: sigmoid(bufA @ Wd2 + bd2) -> d_out (fp32) ----
    mm_mfma_kernel<64, 2><<<gMM, blk, 0, stream>>>(bufA, Pd2, bd2, nullptr, (float*)d_out);
}

// Round 7
// 372.156 us; speedup vs baseline: 13.6138x; 1.0284x over previous
//
#include <hip/hip_runtime.h>
#include <hip/hip_bf16.h>

#define N_NODES 50000
#define N_EDGES 800000
#define C_H 128
#define C_OUT 64
#define NBLK 196          // ceil(50000/256)

typedef __attribute__((ext_vector_type(8))) short bf16x8;
typedef __attribute__((ext_vector_type(4))) float f32x4;

static __device__ __forceinline__ float bf_lo(unsigned int u) { return __uint_as_float(u << 16); }
static __device__ __forceinline__ float bf_hi(unsigned int u) { return __uint_as_float(u & 0xffff0000u); }
static __device__ __forceinline__ unsigned short f2bf(float f) {
    __hip_bfloat16 h = __float2bfloat16(f);
    return *(unsigned short*)&h;
}
static __device__ __forceinline__ unsigned int pack2(float a, float b) {
    return (unsigned int)f2bf(a) | ((unsigned int)f2bf(b) << 16);
}

// ================= CSR construction =================

__global__ void hist_kernel(const int* __restrict__ dst, int* __restrict__ counts) {
    int e = blockIdx.x * 256 + threadIdx.x;
    if (e < N_EDGES) atomicAdd(&counts[dst[e]], 1);
}

// phase 1: per-block exclusive scan + block sums; also computes dinv
__global__ void __launch_bounds__(256) scan1_kernel(const int* __restrict__ counts,
                                                    int* __restrict__ eblk,
                                                    int* __restrict__ bsum,
                                                    float* __restrict__ dinv) {
    __shared__ int ws[4];
    int i = blockIdx.x * 256 + threadIdx.x;
    int v = (i < N_NODES) ? counts[i] : 0;
    if (i < N_NODES) dinv[i] = rsqrtf((float)v + 1.0f);
    int lane = threadIdx.x & 63, w = threadIdx.x >> 6;
    int x = v;
    #pragma unroll
    for (int off = 1; off < 64; off <<= 1) {
        int t = __shfl_up(x, off, 64);
        if (lane >= off) x += t;
    }
    if (lane == 63) ws[w] = x;
    __syncthreads();
    if (threadIdx.x == 0) {
        int run = 0;
        #pragma unroll
        for (int k = 0; k < 4; ++k) { int t = ws[k]; ws[k] = run; run += t; }
        bsum[blockIdx.x] = run;
    }
    __syncthreads();
    if (i < N_NODES) eblk[i] = x - v + ws[w];
}

// phase 2: single block scans NBLK block sums -> block offsets; writes rowptr[N]
__global__ void __launch_bounds__(256) scan2_kernel(const int* __restrict__ bsum,
                                                    int* __restrict__ bo,
                                                    int* __restrict__ rowptr) {
    __shared__ int ws[4];
    int i = threadIdx.x;
    int v = (i < NBLK) ? bsum[i] : 0;
    int lane = i & 63, w = i >> 6;
    int x = v;
    #pragma unroll
    for (int off = 1; off < 64; off <<= 1) {
        int t = __shfl_up(x, off, 64);
        if (lane >= off) x += t;
    }
    if (lane == 63) ws[w] = x;
    __syncthreads();
    if (i == 0) {
        int run = 0;
        #pragma unroll
        for (int k = 0; k < 4; ++k) { int t = ws[k]; ws[k] = run; run += t; }
    }
    __syncthreads();
    int excl = x - v + ws[w];
    if (i < NBLK) bo[i] = excl;
    if (i == 255) rowptr[N_NODES] = excl + v;   // v=0 here -> total
}

// phase 3: rowptr = eblk + bo[block]; also init cursor
__global__ void scan3_kernel(const int* __restrict__ eblk, const int* __restrict__ bo,
                             int* __restrict__ rowptr, int* __restrict__ cursor) {
    int i = blockIdx.x * 256 + threadIdx.x;
    if (i < N_NODES) {
        int r = eblk[i] + bo[blockIdx.x];
        rowptr[i] = r;
        cursor[i] = r;
    }
}

// fill packed edge payload: one 8B store per edge {src, norm}
__global__ void csr_fill_kernel(const int* __restrict__ src, const int* __restrict__ dst,
                                const float* __restrict__ dinv,
                                int* __restrict__ cursor,
                                uint2* __restrict__ epay) {
    int e = blockIdx.x * 256 + threadIdx.x;
    if (e < N_EDGES) {
        int d = dst[e], s = src[e];
        int pos = atomicAdd(&cursor[d], 1);
        uint2 p;
        p.x = (unsigned int)s;
        p.y = __float_as_uint(dinv[s] * dinv[d]);
        epay[pos] = p;
    }
}

// ================= combined W packing into MFMA fragment order =================
// layout per weight: P[(((kb*NB)+nb)*64 + lane)*8 + j] = W[kb*32+(lane>>4)*8+j][nb*16+(lane&15)]
__global__ void pack_all_kernel(const float* __restrict__ W1, const float* __restrict__ W2,
                                const float* __restrict__ W3, const float* __restrict__ Wd1,
                                const float* __restrict__ Wd2,
                                unsigned short* __restrict__ P1, unsigned short* __restrict__ P2,
                                unsigned short* __restrict__ P3, unsigned short* __restrict__ Pd1,
                                unsigned short* __restrict__ Pd2) {
    int idx = blockIdx.x * 256 + threadIdx.x;
    if (idx < 4 * 16384) {                       // four 128x128 weights
        int which = idx >> 14;
        int r = idx & 16383;
        const float* W = (which == 0) ? W1 : (which == 1) ? W2 : (which == 2) ? W3 : Wd1;
        unsigned short* P = (which == 0) ? P1 : (which == 1) ? P2 : (which == 2) ? P3 : Pd1;
        int j = r & 7, lane = (r >> 3) & 63, t = r >> 9;
        int nb = t & 7, kb = t >> 3;             // NB=8
        int k = kb * 32 + ((lane >> 4) << 3) + j;
        int n = nb * 16 + (lane & 15);
        P[r] = f2bf(W[(size_t)k * 128 + n]);
    } else {
        int r = idx - 65536;                     // 128x64 weight
        if (r < 8192) {
            int j = r & 7, lane = (r >> 3) & 63, t = r >> 9;
            int nb = t & 3, kb = t >> 2;         // NB=4
            int k = kb * 32 + ((lane >> 4) << 3) + j;
            int n = nb * 16 + (lane & 15);
            Pd2[r] = f2bf(Wd2[(size_t)k * 64 + n]);
        }
    }
}

// ================= MFMA matmul =================
// out = act(in @ W + b); one wave -> 16 rows x COUT.
// IN_F32: read fp32 input (layer 1), convert in-register; else bf16 input.
// OUT_MODE: 0 = bf16, no bias/act; 1 = bf16, bias+relu; 2 = fp32, bias+sigmoid
template <int COUT, int OUT_MODE, bool IN_F32>
__global__ void __launch_bounds__(256) mm_mfma_kernel(
        const unsigned short* __restrict__ hin,
        const float* __restrict__ xin,
        const unsigned short* __restrict__ Wp,
        const float* __restrict__ bias,
        unsigned short* __restrict__ out_b,
        float* __restrict__ out_f) {
    constexpr int NB = COUT / 16;
    const int lane = threadIdx.x & 63;
    const int wave = threadIdx.x >> 6;
    const int wid  = blockIdx.x * 4 + wave;
    if (wid * 16 >= N_NODES) return;
    const int node = wid * 16 + (lane & 15);
    const int quad = lane >> 4;

    f32x4 acc[NB];
    #pragma unroll
    for (int nb = 0; nb < NB; ++nb) acc[nb] = (f32x4){0.f, 0.f, 0.f, 0.f};

    #pragma unroll
    for (int kb = 0; kb < 4; ++kb) {
        bf16x8 hf;
        if (IN_F32) {
            const float* p = xin + (size_t)node * 128 + kb * 32 + quad * 8;
            float4 lo = *(const float4*)p;
            float4 hi = *(const float4*)(p + 4);
            union { bf16x8 v; unsigned int u[4]; } tmp;
            tmp.u[0] = pack2(lo.x, lo.y); tmp.u[1] = pack2(lo.z, lo.w);
            tmp.u[2] = pack2(hi.x, hi.y); tmp.u[3] = pack2(hi.z, hi.w);
            hf = tmp.v;
        } else {
            hf = *(const bf16x8*)(hin + (size_t)node * 128 + kb * 32 + quad * 8);
        }
        #pragma unroll
        for (int nb = 0; nb < NB; ++nb) {
            bf16x8 wf = *(const bf16x8*)(Wp + ((size_t)(kb * NB + nb) * 64 + lane) * 8);
            // D[n][m]: W-frag as A, h-frag as B -> 4 consecutive channels per lane.
            acc[nb] = __builtin_amdgcn_mfma_f32_16x16x32_bf16(wf, hf, acc[nb], 0, 0, 0);
        }
    }

    #pragma unroll
    for (int nb = 0; nb < NB; ++nb) {
        int ch = nb * 16 + quad * 4;
        float vx = acc[nb][0], vy = acc[nb][1], vz = acc[nb][2], vw = acc[nb][3];
        if (OUT_MODE >= 1) {
            float4 b4 = *(const float4*)(bias + ch);
            vx += b4.x; vy += b4.y; vz += b4.z; vw += b4.w;
        }
        if (OUT_MODE == 1) {
            vx = fmaxf(vx, 0.f); vy = fmaxf(vy, 0.f);
            vz = fmaxf(vz, 0.f); vw = fmaxf(vw, 0.f);
        }
        if (OUT_MODE == 2) {
            vx = 1.f / (1.f + expf(-vx)); vy = 1.f / (1.f + expf(-vy));
            vz = 1.f / (1.f + expf(-vz)); vw = 1.f / (1.f + expf(-vw));
            *(float4*)(out_f + (size_t)node * COUT + ch) = make_float4(vx, vy, vz, vw);
        } else {
            uint2 o;
            o.x = pack2(vx, vy);
            o.y = pack2(vz, vw);
            *(uint2*)(out_b + (size_t)node * COUT + ch) = o;
        }
    }
}

// ================= fused gather-aggregate (bf16 in/out) =================
// 16 lanes per node, 8 channels per lane. out = relu(sum + selfloop + bias), bf16.
__global__ void __launch_bounds__(256) gather_agg_kernel(
        const int* __restrict__ rowptr,
        const uint2* __restrict__ epay,
        const float* __restrict__ dinv,
        const unsigned short* __restrict__ h,
        const float* __restrict__ bias,
        unsigned short* __restrict__ out) {
    int t    = blockIdx.x * 256 + threadIdx.x;
    int node = t >> 4;
    int c8   = (t & 15) << 3;
    if (node >= N_NODES) return;

    float di = dinv[node];
    float dii = di * di;
    uint4 raw = *(const uint4*)(h + (size_t)node * C_H + c8);
    float a0 = bf_lo(raw.x) * dii, a1 = bf_hi(raw.x) * dii;
    float a2 = bf_lo(raw.y) * dii, a3 = bf_hi(raw.y) * dii;
    float a4 = bf_lo(raw.z) * dii, a5 = bf_hi(raw.z) * dii;
    float a6 = bf_lo(raw.w) * dii, a7 = bf_hi(raw.w) * dii;

    int beg = rowptr[node], end = rowptr[node + 1];
    for (int p = beg; p < end; ++p) {
        uint2 ep = epay[p];
        int s = (int)ep.x;
        float nrm = __uint_as_float(ep.y);
        uint4 rv = *(const uint4*)(h + (size_t)s * C_H + c8);
        a0 = fmaf(bf_lo(rv.x), nrm, a0); a1 = fmaf(bf_hi(rv.x), nrm, a1);
        a2 = fmaf(bf_lo(rv.y), nrm, a2); a3 = fmaf(bf_hi(rv.y), nrm, a3);
        a4 = fmaf(bf_lo(rv.z), nrm, a4); a5 = fmaf(bf_hi(rv.z), nrm, a5);
        a6 = fmaf(bf_lo(rv.w), nrm, a6); a7 = fmaf(bf_hi(rv.w), nrm, a7);
    }

    float4 ba = *(const float4*)(bias + c8);
    float4 bb = *(const float4*)(bias + c8 + 4);
    a0 = fmaxf(a0 + ba.x, 0.f); a1 = fmaxf(a1 + ba.y, 0.f);
    a2 = fmaxf(a2 + ba.z, 0.f); a3 = fmaxf(a3 + ba.w, 0.f);
    a4 = fmaxf(a4 + bb.x, 0.f); a5 = fmaxf(a5 + bb.y, 0.f);
    a6 = fmaxf(a6 + bb.z, 0.f); a7 = fmaxf(a7 + bb.w, 0.f);

    uint4 o;
    o.x = pack2(a0, a1); o.y = pack2(a2, a3);
    o.z = pack2(a4, a5); o.w = pack2(a6, a7);
    *(uint4*)(out + (size_t)node * C_H + c8) = o;
}

extern "C" void kernel_launch(void* const* d_in, const int* in_sizes, int n_in,
                              void* d_out, int out_size, void* d_ws, size_t ws_size,
                              hipStream_t stream) {
    const float* x   = (const float*)d_in[0];
    const int*   ei  = (const int*)d_in[1];
    const float* W1  = (const float*)d_in[2];
    const float* b1  = (const float*)d_in[3];
    const float* W2  = (const float*)d_in[4];
    const float* b2  = (const float*)d_in[5];
    const float* W3  = (const float*)d_in[6];
    const float* b3  = (const float*)d_in[7];
    const float* Wd1 = (const float*)d_in[8];
    const float* bd1 = (const float*)d_in[9];
    const float* Wd2 = (const float*)d_in[10];
    const float* bd2 = (const float*)d_in[11];

    const int* src = ei;
    const int* dst = ei + N_EDGES;

    // ---- workspace layout ----
    char* base = (char*)d_ws;
    size_t off = 0;
    auto alloc = [&](size_t bytes) { char* p = base + off; off += (bytes + 255) & ~size_t(255); return p; };
    float*          dinv   = (float*)alloc(N_NODES * 4);
    int*            counts = (int*)alloc(N_NODES * 4);
    int*            rowptr = (int*)alloc((N_NODES + 1) * 4);
    int*            cursor = (int*)alloc(N_NODES * 4);
    int*            eblk   = (int*)alloc(N_NODES * 4);
    int*            bsum   = (int*)alloc(256 * 4);
    int*            bo     = (int*)alloc(256 * 4);
    uint2*          epay   = (uint2*)alloc((size_t)N_EDGES * 8);
    unsigned short* bufA   = (unsigned short*)alloc((size_t)N_NODES * C_H * 2);
    unsigned short* bufB   = (unsigned short*)alloc((size_t)N_NODES * C_H * 2);
    unsigned short* P1     = (unsigned short*)alloc(128 * 128 * 2);
    unsigned short* P2     = (unsigned short*)alloc(128 * 128 * 2);
    unsigned short* P3     = (unsigned short*)alloc(128 * 128 * 2);
    unsigned short* Pd1    = (unsigned short*)alloc(128 * 128 * 2);
    unsigned short* Pd2    = (unsigned short*)alloc(128 * 64 * 2);

    const int T = 256;
    dim3 blk(T);
    dim3 gN((N_NODES + T - 1) / T);          // 196
    dim3 gE((N_EDGES + T - 1) / T);
    dim3 gMM((N_NODES / 16 + 3) / 4);        // 782 blocks, 4 waves each
    dim3 gAgg((N_NODES * 16 + T - 1) / T);   // 3125
    dim3 gPak((4 * 16384 + 8192 + T - 1) / T); // 288

    // ---- CSR + norms ----
    hipMemsetAsync(counts, 0, N_NODES * 4, stream);
    hist_kernel<<<gE, blk, 0, stream>>>(dst, counts);
    scan1_kernel<<<gN, blk, 0, stream>>>(counts, eblk, bsum, dinv);
    scan2_kernel<<<1, blk, 0, stream>>>(bsum, bo, rowptr);
    scan3_kernel<<<gN, blk, 0, stream>>>(eblk, bo, rowptr, cursor);
    csr_fill_kernel<<<gE, blk, 0, stream>>>(src, dst, dinv, cursor, epay);

    // ---- weight packing (single kernel) ----
    pack_all_kernel<<<gPak, blk, 0, stream>>>(W1, W2, W3, Wd1, Wd2, P1, P2, P3, Pd1, Pd2);

    // ---- GCN layer 1 (fp32 x consumed directly) ----
    mm_mfma_kernel<128, 0, true><<<gMM, blk, 0, stream>>>(nullptr, x, P1, nullptr, bufA, nullptr);
    gather_agg_kernel<<<gAgg, blk, 0, stream>>>(rowptr, epay, dinv, bufA, b1, bufB);
    // ---- GCN layer 2 ----
    mm_mfma_kernel<128, 0, false><<<gMM, blk, 0, stream>>>(bufB, nullptr, P2, nullptr, bufA, nullptr);
    gather_agg_kernel<<<gAgg, blk, 0, stream>>>(rowptr, epay, dinv, bufA, b2, bufB);
    // ---- GCN layer 3 ----
    mm_mfma_kernel<128, 0, false><<<gMM, blk, 0, stream>>>(bufB, nullptr, P3, nullptr, bufA, nullptr);
    gather_agg_kernel<<<gAgg, blk, 0, stream>>>(rowptr, epay, dinv, bufA, b3, bufB);

    // ---- dense 1: relu(bufB @ Wd1 + bd1) -> bufA (bf16) ----
    mm_mfma_kernel<128, 1, false><<<gMM, blk, 0, stream>>>(bufB, nullptr, Pd1, bd1, bufA, nullptr);
    // ---- dense 2: sigmoid(bufA @ Wd2 + bd2) -> d_out (fp32) ----
    mm_mfma_kernel<64, 2, false><<<gMM, blk, 0, stream>>>(bufA, nullptr, Pd2, bd2, nullptr, (float*)d_out);
}

// Round 8
// 317.557 us; speedup vs baseline: 15.9545x; 1.1719x over previous
//
#include <hip/hip_runtime.h>
#include <hip/hip_bf16.h>

#define N_NODES 50000
#define N_EDGES 800000
#define C_H 128
#define C_OUT 64
#define NBLK 196          // ceil(50000/256)
#define TSTRIDE 136       // LDS tile row stride in bf16 (128 + 8 pad -> bank shift 4)

typedef __attribute__((ext_vector_type(8))) short bf16x8;
typedef __attribute__((ext_vector_type(4))) float f32x4;

static __device__ __forceinline__ float bf_lo(unsigned int u) { return __uint_as_float(u << 16); }
static __device__ __forceinline__ float bf_hi(unsigned int u) { return __uint_as_float(u & 0xffff0000u); }
static __device__ __forceinline__ unsigned short f2bf(float f) {
    __hip_bfloat16 h = __float2bfloat16(f);
    return *(unsigned short*)&h;
}
static __device__ __forceinline__ unsigned int pack2(float a, float b) {
    return (unsigned int)f2bf(a) | ((unsigned int)f2bf(b) << 16);
}

// ================= CSR construction =================

__global__ void hist_kernel(const int* __restrict__ dst, int* __restrict__ counts) {
    int e = blockIdx.x * 256 + threadIdx.x;
    if (e < N_EDGES) atomicAdd(&counts[dst[e]], 1);
}

__global__ void __launch_bounds__(256) scan1_kernel(const int* __restrict__ counts,
                                                    int* __restrict__ eblk,
                                                    int* __restrict__ bsum,
                                                    float* __restrict__ dinv) {
    __shared__ int ws[4];
    int i = blockIdx.x * 256 + threadIdx.x;
    int v = (i < N_NODES) ? counts[i] : 0;
    if (i < N_NODES) dinv[i] = rsqrtf((float)v + 1.0f);
    int lane = threadIdx.x & 63, w = threadIdx.x >> 6;
    int x = v;
    #pragma unroll
    for (int off = 1; off < 64; off <<= 1) {
        int t = __shfl_up(x, off, 64);
        if (lane >= off) x += t;
    }
    if (lane == 63) ws[w] = x;
    __syncthreads();
    if (threadIdx.x == 0) {
        int run = 0;
        #pragma unroll
        for (int k = 0; k < 4; ++k) { int t = ws[k]; ws[k] = run; run += t; }
        bsum[blockIdx.x] = run;
    }
    __syncthreads();
    if (i < N_NODES) eblk[i] = x - v + ws[w];
}

__global__ void __launch_bounds__(256) scan2_kernel(const int* __restrict__ bsum,
                                                    int* __restrict__ bo,
                                                    int* __restrict__ rowptr) {
    __shared__ int ws[4];
    int i = threadIdx.x;
    int v = (i < NBLK) ? bsum[i] : 0;
    int lane = i & 63, w = i >> 6;
    int x = v;
    #pragma unroll
    for (int off = 1; off < 64; off <<= 1) {
        int t = __shfl_up(x, off, 64);
        if (lane >= off) x += t;
    }
    if (lane == 63) ws[w] = x;
    __syncthreads();
    if (i == 0) {
        int run = 0;
        #pragma unroll
        for (int k = 0; k < 4; ++k) { int t = ws[k]; ws[k] = run; run += t; }
    }
    __syncthreads();
    int excl = x - v + ws[w];
    if (i < NBLK) bo[i] = excl;
    if (i == 255) rowptr[N_NODES] = excl + v;
}

__global__ void scan3_kernel(const int* __restrict__ eblk, const int* __restrict__ bo,
                             int* __restrict__ rowptr, int* __restrict__ cursor) {
    int i = blockIdx.x * 256 + threadIdx.x;
    if (i < N_NODES) {
        int r = eblk[i] + bo[blockIdx.x];
        rowptr[i] = r;
        cursor[i] = r;
    }
}

__global__ void csr_fill_kernel(const int* __restrict__ src, const int* __restrict__ dst,
                                const float* __restrict__ dinv,
                                int* __restrict__ cursor,
                                uint2* __restrict__ epay) {
    int e = blockIdx.x * 256 + threadIdx.x;
    if (e < N_EDGES) {
        int d = dst[e], s = src[e];
        int pos = atomicAdd(&cursor[d], 1);
        uint2 p;
        p.x = (unsigned int)s;
        p.y = __float_as_uint(dinv[s] * dinv[d]);
        epay[pos] = p;
    }
}

// ================= combined W packing into MFMA fragment order =================
__global__ void pack_all_kernel(const float* __restrict__ W1, const float* __restrict__ W2,
                                const float* __restrict__ W3, const float* __restrict__ Wd1,
                                const float* __restrict__ Wd2,
                                unsigned short* __restrict__ P1, unsigned short* __restrict__ P2,
                                unsigned short* __restrict__ P3, unsigned short* __restrict__ Pd1,
                                unsigned short* __restrict__ Pd2) {
    int idx = blockIdx.x * 256 + threadIdx.x;
    if (idx < 4 * 16384) {
        int which = idx >> 14;
        int r = idx & 16383;
        const float* W = (which == 0) ? W1 : (which == 1) ? W2 : (which == 2) ? W3 : Wd1;
        unsigned short* P = (which == 0) ? P1 : (which == 1) ? P2 : (which == 2) ? P3 : Pd1;
        int j = r & 7, lane = (r >> 3) & 63, t = r >> 9;
        int nb = t & 7, kb = t >> 3;             // NB=8
        int k = kb * 32 + ((lane >> 4) << 3) + j;
        int n = nb * 16 + (lane & 15);
        P[r] = f2bf(W[(size_t)k * 128 + n]);
    } else {
        int r = idx - 65536;
        if (r < 8192) {
            int j = r & 7, lane = (r >> 3) & 63, t = r >> 9;
            int nb = t & 3, kb = t >> 2;         // NB=4
            int k = kb * 32 + ((lane >> 4) << 3) + j;
            int n = nb * 16 + (lane & 15);
            Pd2[r] = f2bf(Wd2[(size_t)k * 64 + n]);
        }
    }
}

// ================= fp32 -> bf16 convert (x) =================
__global__ void cvt_bf16_kernel(const float* __restrict__ in, unsigned short* __restrict__ out) {
    int i = blockIdx.x * 256 + threadIdx.x;
    if (i >= N_NODES * C_H / 4) return;
    float4 v = *(const float4*)(in + (size_t)i * 4);
    ushort4 u;
    u.x = f2bf(v.x); u.y = f2bf(v.y); u.z = f2bf(v.z); u.w = f2bf(v.w);
    *(ushort4*)(out + (size_t)i * 4) = u;
}

// ================= fused layer: gather(A·H) -> LDS tile -> MFMA chain =================
// Block = 256 threads, exactly 16 nodes/block (3125 blocks * 16 = 50000).
// Phase A: 16 lanes/node aggregate one 128-ch row (fp32 acc) -> bf16 tile in LDS.
// Phase B: 4 waves MFMA the 16x128 tile vs packed W; FINAL chains W3->Wd1->Wd2.
template <bool FINAL>
__global__ void __launch_bounds__(256) fused_layer_kernel(
        const int* __restrict__ rowptr,
        const uint2* __restrict__ epay,
        const float* __restrict__ dinv,
        const unsigned short* __restrict__ hin,
        const unsigned short* __restrict__ Wp,
        const float* __restrict__ bias,
        const unsigned short* __restrict__ Wd1p,
        const float* __restrict__ bd1,
        const unsigned short* __restrict__ Wd2p,
        const float* __restrict__ bd2,
        unsigned short* __restrict__ out_b,
        float* __restrict__ out_f) {
    __shared__ unsigned short sG[16 * TSTRIDE];
    const int t = threadIdx.x;

    // ---- phase A: gather agg row into LDS tile ----
    {
        int nl = t >> 4, c8 = (t & 15) << 3;
        int node = blockIdx.x * 16 + nl;
        float di = dinv[node], dii = di * di;
        uint4 raw = *(const uint4*)(hin + (size_t)node * C_H + c8);
        float a0 = bf_lo(raw.x) * dii, a1 = bf_hi(raw.x) * dii;
        float a2 = bf_lo(raw.y) * dii, a3 = bf_hi(raw.y) * dii;
        float a4 = bf_lo(raw.z) * dii, a5 = bf_hi(raw.z) * dii;
        float a6 = bf_lo(raw.w) * dii, a7 = bf_hi(raw.w) * dii;
        int beg = rowptr[node], end = rowptr[node + 1];
        for (int p = beg; p < end; ++p) {
            uint2 ep = epay[p];
            int s = (int)ep.x;
            float nrm = __uint_as_float(ep.y);
            uint4 rv = *(const uint4*)(hin + (size_t)s * C_H + c8);
            a0 = fmaf(bf_lo(rv.x), nrm, a0); a1 = fmaf(bf_hi(rv.x), nrm, a1);
            a2 = fmaf(bf_lo(rv.y), nrm, a2); a3 = fmaf(bf_hi(rv.y), nrm, a3);
            a4 = fmaf(bf_lo(rv.z), nrm, a4); a5 = fmaf(bf_hi(rv.z), nrm, a5);
            a6 = fmaf(bf_lo(rv.w), nrm, a6); a7 = fmaf(bf_hi(rv.w), nrm, a7);
        }
        uint4 o;
        o.x = pack2(a0, a1); o.y = pack2(a2, a3);
        o.z = pack2(a4, a5); o.w = pack2(a6, a7);
        *(uint4*)(sG + nl * TSTRIDE + c8) = o;
    }
    __syncthreads();

    const int lane = t & 63, wave = t >> 6, quad = lane >> 4, row = lane & 15;
    const int node = blockIdx.x * 16 + row;

    // ---- mm1: tile @ Wp (COUT=128), bias+relu ----
    f32x4 acc0 = (f32x4){0.f, 0.f, 0.f, 0.f};
    f32x4 acc1 = (f32x4){0.f, 0.f, 0.f, 0.f};
    const int nb0 = 2 * wave, nb1 = 2 * wave + 1;
    #pragma unroll
    for (int kb = 0; kb < 4; ++kb) {
        bf16x8 hf = *(const bf16x8*)(sG + row * TSTRIDE + kb * 32 + quad * 8);
        bf16x8 wf0 = *(const bf16x8*)(Wp + ((size_t)(kb * 8 + nb0) * 64 + lane) * 8);
        bf16x8 wf1 = *(const bf16x8*)(Wp + ((size_t)(kb * 8 + nb1) * 64 + lane) * 8);
        acc0 = __builtin_amdgcn_mfma_f32_16x16x32_bf16(wf0, hf, acc0, 0, 0, 0);
        acc1 = __builtin_amdgcn_mfma_f32_16x16x32_bf16(wf1, hf, acc1, 0, 0, 0);
    }
    float4 ba0 = *(const float4*)(bias + nb0 * 16 + quad * 4);
    float4 ba1 = *(const float4*)(bias + nb1 * 16 + quad * 4);
    float v00 = fmaxf(acc0[0] + ba0.x, 0.f), v01 = fmaxf(acc0[1] + ba0.y, 0.f);
    float v02 = fmaxf(acc0[2] + ba0.z, 0.f), v03 = fmaxf(acc0[3] + ba0.w, 0.f);
    float v10 = fmaxf(acc1[0] + ba1.x, 0.f), v11 = fmaxf(acc1[1] + ba1.y, 0.f);
    float v12 = fmaxf(acc1[2] + ba1.z, 0.f), v13 = fmaxf(acc1[3] + ba1.w, 0.f);

    if (!FINAL) {
        uint2 o0, o1;
        o0.x = pack2(v00, v01); o0.y = pack2(v02, v03);
        o1.x = pack2(v10, v11); o1.y = pack2(v12, v13);
        *(uint2*)(out_b + (size_t)node * C_H + nb0 * 16 + quad * 4) = o0;
        *(uint2*)(out_b + (size_t)node * C_H + nb1 * 16 + quad * 4) = o1;
        return;
    }

    // ---- FINAL: H3 -> tile -> Wd1 -> tile -> Wd2 -> sigmoid -> out_f ----
    __syncthreads();   // all tile reads done
    {
        uint2 o0, o1;
        o0.x = pack2(v00, v01); o0.y = pack2(v02, v03);
        o1.x = pack2(v10, v11); o1.y = pack2(v12, v13);
        *(uint2*)(sG + row * TSTRIDE + nb0 * 16 + quad * 4) = o0;
        *(uint2*)(sG + row * TSTRIDE + nb1 * 16 + quad * 4) = o1;
    }
    __syncthreads();

    // mm2: tile @ Wd1 (COUT=128), bias+relu
    acc0 = (f32x4){0.f, 0.f, 0.f, 0.f};
    acc1 = (f32x4){0.f, 0.f, 0.f, 0.f};
    #pragma unroll
    for (int kb = 0; kb < 4; ++kb) {
        bf16x8 hf = *(const bf16x8*)(sG + row * TSTRIDE + kb * 32 + quad * 8);
        bf16x8 wf0 = *(const bf16x8*)(Wd1p + ((size_t)(kb * 8 + nb0) * 64 + lane) * 8);
        bf16x8 wf1 = *(const bf16x8*)(Wd1p + ((size_t)(kb * 8 + nb1) * 64 + lane) * 8);
        acc0 = __builtin_amdgcn_mfma_f32_16x16x32_bf16(wf0, hf, acc0, 0, 0, 0);
        acc1 = __builtin_amdgcn_mfma_f32_16x16x32_bf16(wf1, hf, acc1, 0, 0, 0);
    }
    ba0 = *(const float4*)(bd1 + nb0 * 16 + quad * 4);
    ba1 = *(const float4*)(bd1 + nb1 * 16 + quad * 4);
    v00 = fmaxf(acc0[0] + ba0.x, 0.f); v01 = fmaxf(acc0[1] + ba0.y, 0.f);
    v02 = fmaxf(acc0[2] + ba0.z, 0.f); v03 = fmaxf(acc0[3] + ba0.w, 0.f);
    v10 = fmaxf(acc1[0] + ba1.x, 0.f); v11 = fmaxf(acc1[1] + ba1.y, 0.f);
    v12 = fmaxf(acc1[2] + ba1.z, 0.f); v13 = fmaxf(acc1[3] + ba1.w, 0.f);
    __syncthreads();
    {
        uint2 o0, o1;
        o0.x = pack2(v00, v01); o0.y = pack2(v02, v03);
        o1.x = pack2(v10, v11); o1.y = pack2(v12, v13);
        *(uint2*)(sG + row * TSTRIDE + nb0 * 16 + quad * 4) = o0;
        *(uint2*)(sG + row * TSTRIDE + nb1 * 16 + quad * 4) = o1;
    }
    __syncthreads();

    // mm3: tile @ Wd2 (COUT=64), bias+sigmoid, fp32 out
    f32x4 acc = (f32x4){0.f, 0.f, 0.f, 0.f};
    #pragma unroll
    for (int kb = 0; kb < 4; ++kb) {
        bf16x8 hf = *(const bf16x8*)(sG + row * TSTRIDE + kb * 32 + quad * 8);
        bf16x8 wf = *(const bf16x8*)(Wd2p + ((size_t)(kb * 4 + wave) * 64 + lane) * 8);
        acc = __builtin_amdgcn_mfma_f32_16x16x32_bf16(wf, hf, acc, 0, 0, 0);
    }
    int ch = wave * 16 + quad * 4;
    float4 b4 = *(const float4*)(bd2 + ch);
    float4 r;
    r.x = 1.f / (1.f + expf(-(acc[0] + b4.x)));
    r.y = 1.f / (1.f + expf(-(acc[1] + b4.y)));
    r.z = 1.f / (1.f + expf(-(acc[2] + b4.z)));
    r.w = 1.f / (1.f + expf(-(acc[3] + b4.w)));
    *(float4*)(out_f + (size_t)node * C_OUT + ch) = r;
}

extern "C" void kernel_launch(void* const* d_in, const int* in_sizes, int n_in,
                              void* d_out, int out_size, void* d_ws, size_t ws_size,
                              hipStream_t stream) {
    const float* x   = (const float*)d_in[0];
    const int*   ei  = (const int*)d_in[1];
    const float* W1  = (const float*)d_in[2];
    const float* b1  = (const float*)d_in[3];
    const float* W2  = (const float*)d_in[4];
    const float* b2  = (const float*)d_in[5];
    const float* W3  = (const float*)d_in[6];
    const float* b3  = (const float*)d_in[7];
    const float* Wd1 = (const float*)d_in[8];
    const float* bd1 = (const float*)d_in[9];
    const float* Wd2 = (const float*)d_in[10];
    const float* bd2 = (const float*)d_in[11];

    const int* src = ei;
    const int* dst = ei + N_EDGES;

    char* base = (char*)d_ws;
    size_t off = 0;
    auto alloc = [&](size_t bytes) { char* p = base + off; off += (bytes + 255) & ~size_t(255); return p; };
    float*          dinv   = (float*)alloc(N_NODES * 4);
    int*            counts = (int*)alloc(N_NODES * 4);
    int*            rowptr = (int*)alloc((N_NODES + 1) * 4);
    int*            cursor = (int*)alloc(N_NODES * 4);
    int*            eblk   = (int*)alloc(N_NODES * 4);
    int*            bsum   = (int*)alloc(256 * 4);
    int*            bo     = (int*)alloc(256 * 4);
    uint2*          epay   = (uint2*)alloc((size_t)N_EDGES * 8);
    unsigned short* xb     = (unsigned short*)alloc((size_t)N_NODES * C_H * 2);
    unsigned short* bufA   = (unsigned short*)alloc((size_t)N_NODES * C_H * 2);
    unsigned short* bufB   = (unsigned short*)alloc((size_t)N_NODES * C_H * 2);
    unsigned short* P1     = (unsigned short*)alloc(128 * 128 * 2);
    unsigned short* P2     = (unsigned short*)alloc(128 * 128 * 2);
    unsigned short* P3     = (unsigned short*)alloc(128 * 128 * 2);
    unsigned short* Pd1    = (unsigned short*)alloc(128 * 128 * 2);
    unsigned short* Pd2    = (unsigned short*)alloc(128 * 64 * 2);

    const int T = 256;
    dim3 blk(T);
    dim3 gN((N_NODES + T - 1) / T);            // 196
    dim3 gE((N_EDGES + T - 1) / T);
    dim3 gCvt((N_NODES * C_H / 4 + T - 1) / T);
    dim3 gFused(N_NODES / 16);                 // 3125, exact
    dim3 gPak((4 * 16384 + 8192 + T - 1) / T);

    // ---- CSR + norms ----
    hipMemsetAsync(counts, 0, N_NODES * 4, stream);
    hist_kernel<<<gE, blk, 0, stream>>>(dst, counts);
    scan1_kernel<<<gN, blk, 0, stream>>>(counts, eblk, bsum, dinv);
    scan2_kernel<<<1, blk, 0, stream>>>(bsum, bo, rowptr);
    scan3_kernel<<<gN, blk, 0, stream>>>(eblk, bo, rowptr, cursor);
    csr_fill_kernel<<<gE, blk, 0, stream>>>(src, dst, dinv, cursor, epay);

    // ---- weight packing + input convert ----
    pack_all_kernel<<<gPak, blk, 0, stream>>>(W1, W2, W3, Wd1, Wd2, P1, P2, P3, Pd1, Pd2);
    cvt_bf16_kernel<<<gCvt, blk, 0, stream>>>(x, xb);

    // ---- layer 1: relu(agg(xb) @ W1 + b1) -> bufA ----
    fused_layer_kernel<false><<<gFused, blk, 0, stream>>>(
        rowptr, epay, dinv, xb, P1, b1, nullptr, nullptr, nullptr, nullptr, bufA, nullptr);
    // ---- layer 2 ----
    fused_layer_kernel<false><<<gFused, blk, 0, stream>>>(
        rowptr, epay, dinv, bufA, P2, b2, nullptr, nullptr, nullptr, nullptr, bufB, nullptr);
    // ---- layer 3 + dense head ----
    fused_layer_kernel<true><<<gFused, blk, 0, stream>>>(
        rowptr, epay, dinv, bufB, P3, b3, Pd1, bd1, Pd2, bd2, nullptr, (float*)d_out);
}

// Round 9
// 280.860 us; speedup vs baseline: 18.0391x; 1.1307x over previous
//
#include <hip/hip_runtime.h>
#include <hip/hip_bf16.h>
#include <hip/hip_fp16.h>

#define N_NODES 50000
#define N_EDGES 800000
#define C_H 128
#define C_OUT 64
#define NBLK 196          // ceil(50000/256)
#define TSTRIDE 136       // LDS tile row stride in bf16
#define E_PAD 950272      // >= N_EDGES + 3*N_NODES, 256-aligned

typedef __attribute__((ext_vector_type(8))) short bf16x8;
typedef __attribute__((ext_vector_type(4))) float f32x4;

static __device__ __forceinline__ float bf_lo(unsigned int u) { return __uint_as_float(u << 16); }
static __device__ __forceinline__ float bf_hi(unsigned int u) { return __uint_as_float(u & 0xffff0000u); }
static __device__ __forceinline__ unsigned short f2bf(float f) {
    __hip_bfloat16 h = __float2bfloat16(f);
    return *(unsigned short*)&h;
}
static __device__ __forceinline__ unsigned int pack2(float a, float b) {
    return (unsigned int)f2bf(a) | ((unsigned int)f2bf(b) << 16);
}
static __device__ __forceinline__ unsigned short f2h_bits(float f) {
    union { __half h; unsigned short u; } c; c.h = __float2half_rn(f); return c.u;
}
static __device__ __forceinline__ float h_bits2f(unsigned short u) {
    union { __half h; unsigned short u; } c; c.u = u; return __half2float(c.h);
}

// ================= merged prep: cvt(x) + hist + pack W =================
__global__ void prep_kernel(const float* __restrict__ x, unsigned short* __restrict__ xb,
                            const int* __restrict__ dst, int* __restrict__ counts,
                            const float* __restrict__ W1, const float* __restrict__ W2,
                            const float* __restrict__ W3, const float* __restrict__ Wd1,
                            const float* __restrict__ Wd2,
                            unsigned short* __restrict__ P1, unsigned short* __restrict__ P2,
                            unsigned short* __restrict__ P3, unsigned short* __restrict__ Pd1,
                            unsigned short* __restrict__ Pd2) {
    int b = blockIdx.x;
    if (b < 6250) {                               // cvt: 1.6M float4 groups
        int i = b * 256 + threadIdx.x;
        float4 v = *(const float4*)(x + (size_t)i * 4);
        ushort4 u;
        u.x = f2bf(v.x); u.y = f2bf(v.y); u.z = f2bf(v.z); u.w = f2bf(v.w);
        *(ushort4*)(xb + (size_t)i * 4) = u;
    } else if (b < 6250 + 3125) {                 // hist over edges
        int e = (b - 6250) * 256 + threadIdx.x;
        atomicAdd(&counts[dst[e]], 1);
    } else {                                      // pack weights
        int idx = (b - 9375) * 256 + threadIdx.x;
        if (idx < 4 * 16384) {
            int which = idx >> 14;
            int r = idx & 16383;
            const float* W = (which == 0) ? W1 : (which == 1) ? W2 : (which == 2) ? W3 : Wd1;
            unsigned short* P = (which == 0) ? P1 : (which == 1) ? P2 : (which == 2) ? P3 : Pd1;
            int j = r & 7, lane = (r >> 3) & 63, t = r >> 9;
            int nb = t & 7, kb = t >> 3;          // NB=8
            int k = kb * 32 + ((lane >> 4) << 3) + j;
            int n = nb * 16 + (lane & 15);
            P[r] = f2bf(W[(size_t)k * 128 + n]);
        } else {
            int r = idx - 65536;
            if (r < 8192) {
                int j = r & 7, lane = (r >> 3) & 63, t = r >> 9;
                int nb = t & 3, kb = t >> 2;      // NB=4
                int k = kb * 32 + ((lane >> 4) << 3) + j;
                int n = nb * 16 + (lane & 15);
                Pd2[r] = f2bf(Wd2[(size_t)k * 64 + n]);
            }
        }
    }
}

// ================= CSR scans (degree padded to multiple of 4) =================
__global__ void __launch_bounds__(256) scan1_kernel(const int* __restrict__ counts,
                                                    int* __restrict__ eblk,
                                                    int* __restrict__ bsum,
                                                    float* __restrict__ dinv) {
    __shared__ int ws[4];
    int i = blockIdx.x * 256 + threadIdx.x;
    int v = (i < N_NODES) ? counts[i] : 0;
    if (i < N_NODES) dinv[i] = rsqrtf((float)v + 1.0f);
    int vp = (v + 3) & ~3;                        // padded degree
    int lane = threadIdx.x & 63, w = threadIdx.x >> 6;
    int x = vp;
    #pragma unroll
    for (int off = 1; off < 64; off <<= 1) {
        int t = __shfl_up(x, off, 64);
        if (lane >= off) x += t;
    }
    if (lane == 63) ws[w] = x;
    __syncthreads();
    if (threadIdx.x == 0) {
        int run = 0;
        #pragma unroll
        for (int k = 0; k < 4; ++k) { int t = ws[k]; ws[k] = run; run += t; }
        bsum[blockIdx.x] = run;
    }
    __syncthreads();
    if (i < N_NODES) eblk[i] = x - vp + ws[w];
}

__global__ void __launch_bounds__(256) scan2_kernel(const int* __restrict__ bsum,
                                                    int* __restrict__ bo,
                                                    int* __restrict__ rowptr) {
    __shared__ int ws[4];
    int i = threadIdx.x;
    int v = (i < NBLK) ? bsum[i] : 0;
    int lane = i & 63, w = i >> 6;
    int x = v;
    #pragma unroll
    for (int off = 1; off < 64; off <<= 1) {
        int t = __shfl_up(x, off, 64);
        if (lane >= off) x += t;
    }
    if (lane == 63) ws[w] = x;
    __syncthreads();
    if (i == 0) {
        int run = 0;
        #pragma unroll
        for (int k = 0; k < 4; ++k) { int t = ws[k]; ws[k] = run; run += t; }
    }
    __syncthreads();
    int excl = x - v + ws[w];
    if (i < NBLK) bo[i] = excl;
    if (i == 255) rowptr[N_NODES] = excl + v;
}

__global__ void scan3_kernel(const int* __restrict__ eblk, const int* __restrict__ bo,
                             int* __restrict__ rowptr, int* __restrict__ cursor) {
    int i = blockIdx.x * 256 + threadIdx.x;
    if (i < N_NODES) {
        int r = eblk[i] + bo[blockIdx.x];
        rowptr[i] = r;
        cursor[i] = r;
    }
}

// fill packed 4B edge payload {u16 src, f16 norm}; pad slots stay 0 (norm=0)
__global__ void csr_fill_kernel(const int* __restrict__ src, const int* __restrict__ dst,
                                const float* __restrict__ dinv,
                                int* __restrict__ cursor,
                                unsigned int* __restrict__ epay) {
    int e = blockIdx.x * 256 + threadIdx.x;
    if (e < N_EDGES) {
        int d = dst[e], s = src[e];
        int pos = atomicAdd(&cursor[d], 1);
        float nrm = dinv[s] * dinv[d];
        epay[pos] = (unsigned int)s | ((unsigned int)f2h_bits(nrm) << 16);
    }
}

// ================= fused layer: gather(A·H) -> LDS tile -> MFMA chain =================
template <bool FINAL>
__global__ void __launch_bounds__(256) fused_layer_kernel(
        const int* __restrict__ rowptr,
        const unsigned int* __restrict__ epay,
        const float* __restrict__ dinv,
        const unsigned short* __restrict__ hin,
        const unsigned short* __restrict__ Wp,
        const float* __restrict__ bias,
        const unsigned short* __restrict__ Wd1p,
        const float* __restrict__ bd1,
        const unsigned short* __restrict__ Wd2p,
        const float* __restrict__ bd2,
        unsigned short* __restrict__ out_b,
        float* __restrict__ out_f) {
    __shared__ unsigned short sG[16 * TSTRIDE];
    const int t = threadIdx.x;

    // ---- phase A: gather agg row into LDS tile, 4 edges/iter ----
    {
        int nl = t >> 4, c8 = (t & 15) << 3;
        int node = blockIdx.x * 16 + nl;
        float di = dinv[node], dii = di * di;
        uint4 raw = *(const uint4*)(hin + (size_t)node * C_H + c8);
        float a0 = bf_lo(raw.x) * dii, a1 = bf_hi(raw.x) * dii;
        float a2 = bf_lo(raw.y) * dii, a3 = bf_hi(raw.y) * dii;
        float a4 = bf_lo(raw.z) * dii, a5 = bf_hi(raw.z) * dii;
        float a6 = bf_lo(raw.w) * dii, a7 = bf_hi(raw.w) * dii;
        int beg = rowptr[node], end = rowptr[node + 1];   // multiples of 4
        for (int p = beg; p < end; p += 4) {
            uint4 ev = *(const uint4*)(epay + p);
            int   s0 = (int)(ev.x & 0xffffu); float n0 = h_bits2f((unsigned short)(ev.x >> 16));
            int   s1 = (int)(ev.y & 0xffffu); float n1 = h_bits2f((unsigned short)(ev.y >> 16));
            int   s2 = (int)(ev.z & 0xffffu); float n2 = h_bits2f((unsigned short)(ev.z >> 16));
            int   s3 = (int)(ev.w & 0xffffu); float n3 = h_bits2f((unsigned short)(ev.w >> 16));
            uint4 r0 = *(const uint4*)(hin + (size_t)s0 * C_H + c8);
            uint4 r1 = *(const uint4*)(hin + (size_t)s1 * C_H + c8);
            uint4 r2 = *(const uint4*)(hin + (size_t)s2 * C_H + c8);
            uint4 r3 = *(const uint4*)(hin + (size_t)s3 * C_H + c8);
            a0 = fmaf(bf_lo(r0.x), n0, a0); a1 = fmaf(bf_hi(r0.x), n0, a1);
            a2 = fmaf(bf_lo(r0.y), n0, a2); a3 = fmaf(bf_hi(r0.y), n0, a3);
            a4 = fmaf(bf_lo(r0.z), n0, a4); a5 = fmaf(bf_hi(r0.z), n0, a5);
            a6 = fmaf(bf_lo(r0.w), n0, a6); a7 = fmaf(bf_hi(r0.w), n0, a7);
            a0 = fmaf(bf_lo(r1.x), n1, a0); a1 = fmaf(bf_hi(r1.x), n1, a1);
            a2 = fmaf(bf_lo(r1.y), n1, a2); a3 = fmaf(bf_hi(r1.y), n1, a3);
            a4 = fmaf(bf_lo(r1.z), n1, a4); a5 = fmaf(bf_hi(r1.z), n1, a5);
            a6 = fmaf(bf_lo(r1.w), n1, a6); a7 = fmaf(bf_hi(r1.w), n1, a7);
            a0 = fmaf(bf_lo(r2.x), n2, a0); a1 = fmaf(bf_hi(r2.x), n2, a1);
            a2 = fmaf(bf_lo(r2.y), n2, a2); a3 = fmaf(bf_hi(r2.y), n2, a3);
            a4 = fmaf(bf_lo(r2.z), n2, a4); a5 = fmaf(bf_hi(r2.z), n2, a5);
            a6 = fmaf(bf_lo(r2.w), n2, a6); a7 = fmaf(bf_hi(r2.w), n2, a7);
            a0 = fmaf(bf_lo(r3.x), n3, a0); a1 = fmaf(bf_hi(r3.x), n3, a1);
            a2 = fmaf(bf_lo(r3.y), n3, a2); a3 = fmaf(bf_hi(r3.y), n3, a3);
            a4 = fmaf(bf_lo(r3.z), n3, a4); a5 = fmaf(bf_hi(r3.z), n3, a5);
            a6 = fmaf(bf_lo(r3.w), n3, a6); a7 = fmaf(bf_hi(r3.w), n3, a7);
        }
        uint4 o;
        o.x = pack2(a0, a1); o.y = pack2(a2, a3);
        o.z = pack2(a4, a5); o.w = pack2(a6, a7);
        *(uint4*)(sG + nl * TSTRIDE + c8) = o;
    }
    __syncthreads();

    const int lane = t & 63, wave = t >> 6, quad = lane >> 4, row = lane & 15;
    const int node = blockIdx.x * 16 + row;

    // ---- mm1: tile @ Wp (COUT=128), bias+relu ----
    f32x4 acc0 = (f32x4){0.f, 0.f, 0.f, 0.f};
    f32x4 acc1 = (f32x4){0.f, 0.f, 0.f, 0.f};
    const int nb0 = 2 * wave, nb1 = 2 * wave + 1;
    #pragma unroll
    for (int kb = 0; kb < 4; ++kb) {
        bf16x8 hf = *(const bf16x8*)(sG + row * TSTRIDE + kb * 32 + quad * 8);
        bf16x8 wf0 = *(const bf16x8*)(Wp + ((size_t)(kb * 8 + nb0) * 64 + lane) * 8);
        bf16x8 wf1 = *(const bf16x8*)(Wp + ((size_t)(kb * 8 + nb1) * 64 + lane) * 8);
        acc0 = __builtin_amdgcn_mfma_f32_16x16x32_bf16(wf0, hf, acc0, 0, 0, 0);
        acc1 = __builtin_amdgcn_mfma_f32_16x16x32_bf16(wf1, hf, acc1, 0, 0, 0);
    }
    float4 ba0 = *(const float4*)(bias + nb0 * 16 + quad * 4);
    float4 ba1 = *(const float4*)(bias + nb1 * 16 + quad * 4);
    float v00 = fmaxf(acc0[0] + ba0.x, 0.f), v01 = fmaxf(acc0[1] + ba0.y, 0.f);
    float v02 = fmaxf(acc0[2] + ba0.z, 0.f), v03 = fmaxf(acc0[3] + ba0.w, 0.f);
    float v10 = fmaxf(acc1[0] + ba1.x, 0.f), v11 = fmaxf(acc1[1] + ba1.y, 0.f);
    float v12 = fmaxf(acc1[2] + ba1.z, 0.f), v13 = fmaxf(acc1[3] + ba1.w, 0.f);

    if (!FINAL) {
        uint2 o0, o1;
        o0.x = pack2(v00, v01); o0.y = pack2(v02, v03);
        o1.x = pack2(v10, v11); o1.y = pack2(v12, v13);
        *(uint2*)(out_b + (size_t)node * C_H + nb0 * 16 + quad * 4) = o0;
        *(uint2*)(out_b + (size_t)node * C_H + nb1 * 16 + quad * 4) = o1;
        return;
    }

    // ---- FINAL: H3 -> tile -> Wd1 -> tile -> Wd2 -> sigmoid -> out_f ----
    __syncthreads();
    {
        uint2 o0, o1;
        o0.x = pack2(v00, v01); o0.y = pack2(v02, v03);
        o1.x = pack2(v10, v11); o1.y = pack2(v12, v13);
        *(uint2*)(sG + row * TSTRIDE + nb0 * 16 + quad * 4) = o0;
        *(uint2*)(sG + row * TSTRIDE + nb1 * 16 + quad * 4) = o1;
    }
    __syncthreads();

    acc0 = (f32x4){0.f, 0.f, 0.f, 0.f};
    acc1 = (f32x4){0.f, 0.f, 0.f, 0.f};
    #pragma unroll
    for (int kb = 0; kb < 4; ++kb) {
        bf16x8 hf = *(const bf16x8*)(sG + row * TSTRIDE + kb * 32 + quad * 8);
        bf16x8 wf0 = *(const bf16x8*)(Wd1p + ((size_t)(kb * 8 + nb0) * 64 + lane) * 8);
        bf16x8 wf1 = *(const bf16x8*)(Wd1p + ((size_t)(kb * 8 + nb1) * 64 + lane) * 8);
        acc0 = __builtin_amdgcn_mfma_f32_16x16x32_bf16(wf0, hf, acc0, 0, 0, 0);
        acc1 = __builtin_amdgcn_mfma_f32_16x16x32_bf16(wf1, hf, acc1, 0, 0, 0);
    }
    ba0 = *(const float4*)(bd1 + nb0 * 16 + quad * 4);
    ba1 = *(const float4*)(bd1 + nb1 * 16 + quad * 4);
    v00 = fmaxf(acc0[0] + ba0.x, 0.f); v01 = fmaxf(acc0[1] + ba0.y, 0.f);
    v02 = fmaxf(acc0[2] + ba0.z, 0.f); v03 = fmaxf(acc0[3] + ba0.w, 0.f);
    v10 = fmaxf(acc1[0] + ba1.x, 0.f); v11 = fmaxf(acc1[1] + ba1.y, 0.f);
    v12 = fmaxf(acc1[2] + ba1.z, 0.f); v13 = fmaxf(acc1[3] + ba1.w, 0.f);
    __syncthreads();
    {
        uint2 o0, o1;
        o0.x = pack2(v00, v01); o0.y = pack2(v02, v03);
        o1.x = pack2(v10, v11); o1.y = pack2(v12, v13);
        *(uint2*)(sG + row * TSTRIDE + nb0 * 16 + quad * 4) = o0;
        *(uint2*)(sG + row * TSTRIDE + nb1 * 16 + quad * 4) = o1;
    }
    __syncthreads();

    f32x4 acc = (f32x4){0.f, 0.f, 0.f, 0.f};
    #pragma unroll
    for (int kb = 0; kb < 4; ++kb) {
        bf16x8 hf = *(const bf16x8*)(sG + row * TSTRIDE + kb * 32 + quad * 8);
        bf16x8 wf = *(const bf16x8*)(Wd2p + ((size_t)(kb * 4 + wave) * 64 + lane) * 8);
        acc = __builtin_amdgcn_mfma_f32_16x16x32_bf16(wf, hf, acc, 0, 0, 0);
    }
    int ch = wave * 16 + quad * 4;
    float4 b4 = *(const float4*)(bd2 + ch);
    float4 r;
    r.x = 1.f / (1.f + expf(-(acc[0] + b4.x)));
    r.y = 1.f / (1.f + expf(-(acc[1] + b4.y)));
    r.z = 1.f / (1.f + expf(-(acc[2] + b4.z)));
    r.w = 1.f / (1.f + expf(-(acc[3] + b4.w)));
    *(float4*)(out_f + (size_t)node * C_OUT + ch) = r;
}

extern "C" void kernel_launch(void* const* d_in, const int* in_sizes, int n_in,
                              void* d_out, int out_size, void* d_ws, size_t ws_size,
                              hipStream_t stream) {
    const float* x   = (const float*)d_in[0];
    const int*   ei  = (const int*)d_in[1];
    const float* W1  = (const float*)d_in[2];
    const float* b1  = (const float*)d_in[3];
    const float* W2  = (const float*)d_in[4];
    const float* b2  = (const float*)d_in[5];
    const float* W3  = (const float*)d_in[6];
    const float* b3  = (const float*)d_in[7];
    const float* Wd1 = (const float*)d_in[8];
    const float* bd1 = (const float*)d_in[9];
    const float* Wd2 = (const float*)d_in[10];
    const float* bd2 = (const float*)d_in[11];

    const int* src = ei;
    const int* dst = ei + N_EDGES;

    char* base = (char*)d_ws;
    size_t off = 0;
    auto alloc = [&](size_t bytes) { char* p = base + off; off += (bytes + 255) & ~size_t(255); return p; };
    // counts then epay must be contiguous (one memset covers both)
    int*            counts = (int*)alloc(50176 * 4);               // 200704 B
    unsigned int*   epay   = (unsigned int*)alloc((size_t)E_PAD * 4);
    float*          dinv   = (float*)alloc(N_NODES * 4);
    int*            rowptr = (int*)alloc((N_NODES + 1) * 4);
    int*            cursor = (int*)alloc(N_NODES * 4);
    int*            eblk   = (int*)alloc(N_NODES * 4);
    int*            bsum   = (int*)alloc(256 * 4);
    int*            bo     = (int*)alloc(256 * 4);
    unsigned short* xb     = (unsigned short*)alloc((size_t)N_NODES * C_H * 2);
    unsigned short* bufA   = (unsigned short*)alloc((size_t)N_NODES * C_H * 2);
    unsigned short* bufB   = (unsigned short*)alloc((size_t)N_NODES * C_H * 2);
    unsigned short* P1     = (unsigned short*)alloc(128 * 128 * 2);
    unsigned short* P2     = (unsigned short*)alloc(128 * 128 * 2);
    unsigned short* P3     = (unsigned short*)alloc(128 * 128 * 2);
    unsigned short* Pd1    = (unsigned short*)alloc(128 * 128 * 2);
    unsigned short* Pd2    = (unsigned short*)alloc(128 * 64 * 2);

    const int T = 256;
    dim3 blk(T);
    dim3 gN((N_NODES + T - 1) / T);            // 196
    dim3 gE((N_EDGES + T - 1) / T);            // 3125
    dim3 gPrep(6250 + 3125 + 288);             // cvt + hist + pack
    dim3 gFused(N_NODES / 16);                 // 3125, exact

    // zero counts + epay in one shot
    hipMemsetAsync(counts, 0, 50176 * 4 + (size_t)E_PAD * 4, stream);
    prep_kernel<<<gPrep, blk, 0, stream>>>(x, xb, dst, counts,
                                           W1, W2, W3, Wd1, Wd2, P1, P2, P3, Pd1, Pd2);
    scan1_kernel<<<gN, blk, 0, stream>>>(counts, eblk, bsum, dinv);
    scan2_kernel<<<1, blk, 0, stream>>>(bsum, bo, rowptr);
    scan3_kernel<<<gN, blk, 0, stream>>>(eblk, bo, rowptr, cursor);
    csr_fill_kernel<<<gE, blk, 0, stream>>>(src, dst, dinv, cursor, epay);

    // ---- layer 1..3 ----
    fused_layer_kernel<false><<<gFused, blk, 0, stream>>>(
        rowptr, epay, dinv, xb, P1, b1, nullptr, nullptr, nullptr, nullptr, bufA, nullptr);
    fused_layer_kernel<false><<<gFused, blk, 0, stream>>>(
        rowptr, epay, dinv, bufA, P2, b2, nullptr, nullptr, nullptr, nullptr, bufB, nullptr);
    fused_layer_kernel<true><<<gFused, blk, 0, stream>>>(
        rowptr, epay, dinv, bufB, P3, b3, Pd1, bd1, Pd2, bd2, nullptr, (float*)d_out);
}

// Round 10
// 258.717 us; speedup vs baseline: 19.5831x; 1.0856x over previous
//
#include <hip/hip_runtime.h>
#include <hip/hip_bf16.h>
#include <hip/hip_fp16.h>

#define N_NODES 50000
#define N_EDGES 800000
#define C_H 128
#define C_OUT 64
#define NBLK 196          // ceil(50000/256)
#define TSTRIDE 136       // LDS tile row stride in bf16
#define E_PAD 950272      // >= N_EDGES + 3*N_NODES, 1024-aligned

typedef __attribute__((ext_vector_type(8))) short bf16x8;
typedef __attribute__((ext_vector_type(4))) float f32x4;

static __device__ __forceinline__ float bf_lo(unsigned int u) { return __uint_as_float(u << 16); }
static __device__ __forceinline__ float bf_hi(unsigned int u) { return __uint_as_float(u & 0xffff0000u); }
static __device__ __forceinline__ unsigned short f2bf(float f) {
    __hip_bfloat16 h = __float2bfloat16(f);
    return *(unsigned short*)&h;
}
static __device__ __forceinline__ unsigned int pack2(float a, float b) {
    return (unsigned int)f2bf(a) | ((unsigned int)f2bf(b) << 16);
}
static __device__ __forceinline__ unsigned short f2h_bits(float f) {
    union { __half h; unsigned short u; } c; c.h = __float2half_rn(f); return c.u;
}
static __device__ __forceinline__ float h_bits2f(unsigned short u) {
    union { __half h; unsigned short u; } c; c.u = u; return __half2float(c.h);
}

// ================= merged prep: cvt(x) + hist(+rank) + pack W + zero epay =================
// block ranges: [0,6250) cvt | [6250,9375) hist | [9375,9663) pack | [9663,10591) zero
__global__ void prep_kernel(const float* __restrict__ x, unsigned short* __restrict__ xb,
                            const int* __restrict__ dst, int* __restrict__ counts,
                            int* __restrict__ rank,
                            const float* __restrict__ W1, const float* __restrict__ W2,
                            const float* __restrict__ W3, const float* __restrict__ Wd1,
                            const float* __restrict__ Wd2,
                            unsigned short* __restrict__ P1, unsigned short* __restrict__ P2,
                            unsigned short* __restrict__ P3, unsigned short* __restrict__ Pd1,
                            unsigned short* __restrict__ Pd2,
                            unsigned int* __restrict__ epay) {
    int b = blockIdx.x;
    if (b < 6250) {                               // cvt: 1.6M float4 groups
        int i = b * 256 + threadIdx.x;
        float4 v = *(const float4*)(x + (size_t)i * 4);
        ushort4 u;
        u.x = f2bf(v.x); u.y = f2bf(v.y); u.z = f2bf(v.z); u.w = f2bf(v.w);
        *(ushort4*)(xb + (size_t)i * 4) = u;
    } else if (b < 9375) {                        // hist over edges, capture rank
        int e = (b - 6250) * 256 + threadIdx.x;
        rank[e] = atomicAdd(&counts[dst[e]], 1);
    } else if (b < 9663) {                        // pack weights
        int idx = (b - 9375) * 256 + threadIdx.x;
        if (idx < 4 * 16384) {
            int which = idx >> 14;
            int r = idx & 16383;
            const float* W = (which == 0) ? W1 : (which == 1) ? W2 : (which == 2) ? W3 : Wd1;
            unsigned short* P = (which == 0) ? P1 : (which == 1) ? P2 : (which == 2) ? P3 : Pd1;
            int j = r & 7, lane = (r >> 3) & 63, t = r >> 9;
            int nb = t & 7, kb = t >> 3;          // NB=8
            int k = kb * 32 + ((lane >> 4) << 3) + j;
            int n = nb * 16 + (lane & 15);
            P[r] = f2bf(W[(size_t)k * 128 + n]);
        } else {
            int r = idx - 65536;
            if (r < 8192) {
                int j = r & 7, lane = (r >> 3) & 63, t = r >> 9;
                int nb = t & 3, kb = t >> 2;      // NB=4
                int k = kb * 32 + ((lane >> 4) << 3) + j;
                int n = nb * 16 + (lane & 15);
                Pd2[r] = f2bf(Wd2[(size_t)k * 64 + n]);
            }
        }
    } else {                                      // zero epay: 928 blocks x 256 x uint4
        int i = (b - 9663) * 256 + threadIdx.x;
        *(uint4*)(epay + (size_t)i * 4) = make_uint4(0, 0, 0, 0);
    }
}

// ================= CSR scans (degree padded to multiple of 4) =================
__global__ void __launch_bounds__(256) scan1_kernel(const int* __restrict__ counts,
                                                    int* __restrict__ eblk,
                                                    int* __restrict__ bsum,
                                                    float* __restrict__ dinv) {
    __shared__ int ws[4];
    int i = blockIdx.x * 256 + threadIdx.x;
    int v = (i < N_NODES) ? counts[i] : 0;
    if (i < N_NODES) dinv[i] = rsqrtf((float)v + 1.0f);
    int vp = (v + 3) & ~3;                        // padded degree
    int lane = threadIdx.x & 63, w = threadIdx.x >> 6;
    int x = vp;
    #pragma unroll
    for (int off = 1; off < 64; off <<= 1) {
        int t = __shfl_up(x, off, 64);
        if (lane >= off) x += t;
    }
    if (lane == 63) ws[w] = x;
    __syncthreads();
    if (threadIdx.x == 0) {
        int run = 0;
        #pragma unroll
        for (int k = 0; k < 4; ++k) { int t = ws[k]; ws[k] = run; run += t; }
        bsum[blockIdx.x] = run;
    }
    __syncthreads();
    if (i < N_NODES) eblk[i] = x - vp + ws[w];
}

__global__ void __launch_bounds__(256) scan2_kernel(const int* __restrict__ bsum,
                                                    int* __restrict__ bo,
                                                    int* __restrict__ rowptr) {
    __shared__ int ws[4];
    int i = threadIdx.x;
    int v = (i < NBLK) ? bsum[i] : 0;
    int lane = i & 63, w = i >> 6;
    int x = v;
    #pragma unroll
    for (int off = 1; off < 64; off <<= 1) {
        int t = __shfl_up(x, off, 64);
        if (lane >= off) x += t;
    }
    if (lane == 63) ws[w] = x;
    __syncthreads();
    if (i == 0) {
        int run = 0;
        #pragma unroll
        for (int k = 0; k < 4; ++k) { int t = ws[k]; ws[k] = run; run += t; }
    }
    __syncthreads();
    int excl = x - v + ws[w];
    if (i < NBLK) bo[i] = excl;
    if (i == 255) rowptr[N_NODES] = excl + v;
}

__global__ void scan3_kernel(const int* __restrict__ eblk, const int* __restrict__ bo,
                             int* __restrict__ rowptr) {
    int i = blockIdx.x * 256 + threadIdx.x;
    if (i < N_NODES) rowptr[i] = eblk[i] + bo[blockIdx.x];
}

// atomic-free fill: pos = rowptr[d] + rank[e]; pad slots stay 0 (norm=0)
__global__ void csr_fill_kernel(const int* __restrict__ src, const int* __restrict__ dst,
                                const float* __restrict__ dinv,
                                const int* __restrict__ rowptr, const int* __restrict__ rank,
                                unsigned int* __restrict__ epay) {
    int e = blockIdx.x * 256 + threadIdx.x;
    if (e < N_EDGES) {
        int d = dst[e], s = src[e];
        int pos = rowptr[d] + rank[e];
        float nrm = dinv[s] * dinv[d];
        epay[pos] = (unsigned int)s | ((unsigned int)f2h_bits(nrm) << 16);
    }
}

// ================= fused layer: gather(A·H) -> LDS tile -> MFMA chain =================
template <bool FINAL>
__global__ void __launch_bounds__(256) fused_layer_kernel(
        const int* __restrict__ rowptr,
        const unsigned int* __restrict__ epay,
        const float* __restrict__ dinv,
        const unsigned short* __restrict__ hin,
        const unsigned short* __restrict__ Wp,
        const float* __restrict__ bias,
        const unsigned short* __restrict__ Wd1p,
        const float* __restrict__ bd1,
        const unsigned short* __restrict__ Wd2p,
        const float* __restrict__ bd2,
        unsigned short* __restrict__ out_b,
        float* __restrict__ out_f) {
    __shared__ unsigned short sG[16 * TSTRIDE];
    const int t = threadIdx.x;

    // ---- phase A: gather agg row into LDS tile, 8 edges in flight ----
    {
        int nl = t >> 4, c8 = (t & 15) << 3;
        int node = blockIdx.x * 16 + nl;
        float di = dinv[node], dii = di * di;
        uint4 raw = *(const uint4*)(hin + (size_t)node * C_H + c8);
        float a0 = bf_lo(raw.x) * dii, a1 = bf_hi(raw.x) * dii;
        float a2 = bf_lo(raw.y) * dii, a3 = bf_hi(raw.y) * dii;
        float a4 = bf_lo(raw.z) * dii, a5 = bf_hi(raw.z) * dii;
        float a6 = bf_lo(raw.w) * dii, a7 = bf_hi(raw.w) * dii;
        int beg = rowptr[node], end = rowptr[node + 1];   // multiples of 4
        int p = beg;
        for (; p + 8 <= end; p += 8) {
            uint4 ev0 = *(const uint4*)(epay + p);
            uint4 ev1 = *(const uint4*)(epay + p + 4);
            unsigned int ee[8] = {ev0.x, ev0.y, ev0.z, ev0.w, ev1.x, ev1.y, ev1.z, ev1.w};
            uint4 rv[8];
            #pragma unroll
            for (int j = 0; j < 8; ++j)
                rv[j] = *(const uint4*)(hin + (size_t)(ee[j] & 0xffffu) * C_H + c8);
            #pragma unroll
            for (int j = 0; j < 8; ++j) {
                float nm = h_bits2f((unsigned short)(ee[j] >> 16));
                a0 = fmaf(bf_lo(rv[j].x), nm, a0); a1 = fmaf(bf_hi(rv[j].x), nm, a1);
                a2 = fmaf(bf_lo(rv[j].y), nm, a2); a3 = fmaf(bf_hi(rv[j].y), nm, a3);
                a4 = fmaf(bf_lo(rv[j].z), nm, a4); a5 = fmaf(bf_hi(rv[j].z), nm, a5);
                a6 = fmaf(bf_lo(rv[j].w), nm, a6); a7 = fmaf(bf_hi(rv[j].w), nm, a7);
            }
        }
        if (p < end) {                            // exactly 4 remain
            uint4 ev = *(const uint4*)(epay + p);
            unsigned int ee[4] = {ev.x, ev.y, ev.z, ev.w};
            uint4 rv[4];
            #pragma unroll
            for (int j = 0; j < 4; ++j)
                rv[j] = *(const uint4*)(hin + (size_t)(ee[j] & 0xffffu) * C_H + c8);
            #pragma unroll
            for (int j = 0; j < 4; ++j) {
                float nm = h_bits2f((unsigned short)(ee[j] >> 16));
                a0 = fmaf(bf_lo(rv[j].x), nm, a0); a1 = fmaf(bf_hi(rv[j].x), nm, a1);
                a2 = fmaf(bf_lo(rv[j].y), nm, a2); a3 = fmaf(bf_hi(rv[j].y), nm, a3);
                a4 = fmaf(bf_lo(rv[j].z), nm, a4); a5 = fmaf(bf_hi(rv[j].z), nm, a5);
                a6 = fmaf(bf_lo(rv[j].w), nm, a6); a7 = fmaf(bf_hi(rv[j].w), nm, a7);
            }
        }
        uint4 o;
        o.x = pack2(a0, a1); o.y = pack2(a2, a3);
        o.z = pack2(a4, a5); o.w = pack2(a6, a7);
        *(uint4*)(sG + nl * TSTRIDE + c8) = o;
    }
    __syncthreads();

    const int lane = t & 63, wave = t >> 6, quad = lane >> 4, row = lane & 15;
    const int node = blockIdx.x * 16 + row;

    // ---- mm1: tile @ Wp (COUT=128), bias+relu ----
    f32x4 acc0 = (f32x4){0.f, 0.f, 0.f, 0.f};
    f32x4 acc1 = (f32x4){0.f, 0.f, 0.f, 0.f};
    const int nb0 = 2 * wave, nb1 = 2 * wave + 1;
    #pragma unroll
    for (int kb = 0; kb < 4; ++kb) {
        bf16x8 hf = *(const bf16x8*)(sG + row * TSTRIDE + kb * 32 + quad * 8);
        bf16x8 wf0 = *(const bf16x8*)(Wp + ((size_t)(kb * 8 + nb0) * 64 + lane) * 8);
        bf16x8 wf1 = *(const bf16x8*)(Wp + ((size_t)(kb * 8 + nb1) * 64 + lane) * 8);
        acc0 = __builtin_amdgcn_mfma_f32_16x16x32_bf16(wf0, hf, acc0, 0, 0, 0);
        acc1 = __builtin_amdgcn_mfma_f32_16x16x32_bf16(wf1, hf, acc1, 0, 0, 0);
    }
    float4 ba0 = *(const float4*)(bias + nb0 * 16 + quad * 4);
    float4 ba1 = *(const float4*)(bias + nb1 * 16 + quad * 4);
    float v00 = fmaxf(acc0[0] + ba0.x, 0.f), v01 = fmaxf(acc0[1] + ba0.y, 0.f);
    float v02 = fmaxf(acc0[2] + ba0.z, 0.f), v03 = fmaxf(acc0[3] + ba0.w, 0.f);
    float v10 = fmaxf(acc1[0] + ba1.x, 0.f), v11 = fmaxf(acc1[1] + ba1.y, 0.f);
    float v12 = fmaxf(acc1[2] + ba1.z, 0.f), v13 = fmaxf(acc1[3] + ba1.w, 0.f);

    if (!FINAL) {
        uint2 o0, o1;
        o0.x = pack2(v00, v01); o0.y = pack2(v02, v03);
        o1.x = pack2(v10, v11); o1.y = pack2(v12, v13);
        *(uint2*)(out_b + (size_t)node * C_H + nb0 * 16 + quad * 4) = o0;
        *(uint2*)(out_b + (size_t)node * C_H + nb1 * 16 + quad * 4) = o1;
        return;
    }

    // ---- FINAL: H3 -> tile -> Wd1 -> tile -> Wd2 -> sigmoid -> out_f ----
    __syncthreads();
    {
        uint2 o0, o1;
        o0.x = pack2(v00, v01); o0.y = pack2(v02, v03);
        o1.x = pack2(v10, v11); o1.y = pack2(v12, v13);
        *(uint2*)(sG + row * TSTRIDE + nb0 * 16 + quad * 4) = o0;
        *(uint2*)(sG + row * TSTRIDE + nb1 * 16 + quad * 4) = o1;
    }
    __syncthreads();

    acc0 = (f32x4){0.f, 0.f, 0.f, 0.f};
    acc1 = (f32x4){0.f, 0.f, 0.f, 0.f};
    #pragma unroll
    for (int kb = 0; kb < 4; ++kb) {
        bf16x8 hf = *(const bf16x8*)(sG + row * TSTRIDE + kb * 32 + quad * 8);
        bf16x8 wf0 = *(const bf16x8*)(Wd1p + ((size_t)(kb * 8 + nb0) * 64 + lane) * 8);
        bf16x8 wf1 = *(const bf16x8*)(Wd1p + ((size_t)(kb * 8 + nb1) * 64 + lane) * 8);
        acc0 = __builtin_amdgcn_mfma_f32_16x16x32_bf16(wf0, hf, acc0, 0, 0, 0);
        acc1 = __builtin_amdgcn_mfma_f32_16x16x32_bf16(wf1, hf, acc1, 0, 0, 0);
    }
    ba0 = *(const float4*)(bd1 + nb0 * 16 + quad * 4);
    ba1 = *(const float4*)(bd1 + nb1 * 16 + quad * 4);
    v00 = fmaxf(acc0[0] + ba0.x, 0.f); v01 = fmaxf(acc0[1] + ba0.y, 0.f);
    v02 = fmaxf(acc0[2] + ba0.z, 0.f); v03 = fmaxf(acc0[3] + ba0.w, 0.f);
    v10 = fmaxf(acc1[0] + ba1.x, 0.f); v11 = fmaxf(acc1[1] + ba1.y, 0.f);
    v12 = fmaxf(acc1[2] + ba1.z, 0.f); v13 = fmaxf(acc1[3] + ba1.w, 0.f);
    __syncthreads();
    {
        uint2 o0, o1;
        o0.x = pack2(v00, v01); o0.y = pack2(v02, v03);
        o1.x = pack2(v10, v11); o1.y = pack2(v12, v13);
        *(uint2*)(sG + row * TSTRIDE + nb0 * 16 + quad * 4) = o0;
        *(uint2*)(sG + row * TSTRIDE + nb1 * 16 + quad * 4) = o1;
    }
    __syncthreads();

    f32x4 acc = (f32x4){0.f, 0.f, 0.f, 0.f};
    #pragma unroll
    for (int kb = 0; kb < 4; ++kb) {
        bf16x8 hf = *(const bf16x8*)(sG + row * TSTRIDE + kb * 32 + quad * 8);
        bf16x8 wf = *(const bf16x8*)(Wd2p + ((size_t)(kb * 4 + wave) * 64 + lane) * 8);
        acc = __builtin_amdgcn_mfma_f32_16x16x32_bf16(wf, hf, acc, 0, 0, 0);
    }
    int ch = wave * 16 + quad * 4;
    float4 b4 = *(const float4*)(bd2 + ch);
    float4 r;
    r.x = 1.f / (1.f + expf(-(acc[0] + b4.x)));
    r.y = 1.f / (1.f + expf(-(acc[1] + b4.y)));
    r.z = 1.f / (1.f + expf(-(acc[2] + b4.z)));
    r.w = 1.f / (1.f + expf(-(acc[3] + b4.w)));
    *(float4*)(out_f + (size_t)node * C_OUT + ch) = r;
}

extern "C" void kernel_launch(void* const* d_in, const int* in_sizes, int n_in,
                              void* d_out, int out_size, void* d_ws, size_t ws_size,
                              hipStream_t stream) {
    const float* x   = (const float*)d_in[0];
    const int*   ei  = (const int*)d_in[1];
    const float* W1  = (const float*)d_in[2];
    const float* b1  = (const float*)d_in[3];
    const float* W2  = (const float*)d_in[4];
    const float* b2  = (const float*)d_in[5];
    const float* W3  = (const float*)d_in[6];
    const float* b3  = (const float*)d_in[7];
    const float* Wd1 = (const float*)d_in[8];
    const float* bd1 = (const float*)d_in[9];
    const float* Wd2 = (const float*)d_in[10];
    const float* bd2 = (const float*)d_in[11];

    const int* src = ei;
    const int* dst = ei + N_EDGES;

    char* base = (char*)d_ws;
    size_t off = 0;
    auto alloc = [&](size_t bytes) { char* p = base + off; off += (bytes + 255) & ~size_t(255); return p; };
    int*            counts = (int*)alloc(50176 * 4);
    unsigned int*   epay   = (unsigned int*)alloc((size_t)E_PAD * 4);
    int*            rank   = (int*)alloc((size_t)N_EDGES * 4);
    float*          dinv   = (float*)alloc(N_NODES * 4);
    int*            rowptr = (int*)alloc((N_NODES + 1) * 4);
    int*            eblk   = (int*)alloc(N_NODES * 4);
    int*            bsum   = (int*)alloc(256 * 4);
    int*            bo     = (int*)alloc(256 * 4);
    unsigned short* xb     = (unsigned short*)alloc((size_t)N_NODES * C_H * 2);
    unsigned short* bufA   = (unsigned short*)alloc((size_t)N_NODES * C_H * 2);
    unsigned short* bufB   = (unsigned short*)alloc((size_t)N_NODES * C_H * 2);
    unsigned short* P1     = (unsigned short*)alloc(128 * 128 * 2);
    unsigned short* P2     = (unsigned short*)alloc(128 * 128 * 2);
    unsigned short* P3     = (unsigned short*)alloc(128 * 128 * 2);
    unsigned short* Pd1    = (unsigned short*)alloc(128 * 128 * 2);
    unsigned short* Pd2    = (unsigned short*)alloc(128 * 64 * 2);

    const int T = 256;
    dim3 blk(T);
    dim3 gN((N_NODES + T - 1) / T);            // 196
    dim3 gE((N_EDGES + T - 1) / T);            // 3125
    dim3 gPrep(6250 + 3125 + 288 + 928);       // cvt + hist + pack + zero-epay
    dim3 gFused(N_NODES / 16);                 // 3125, exact

    hipMemsetAsync(counts, 0, 50176 * 4, stream);
    prep_kernel<<<gPrep, blk, 0, stream>>>(x, xb, dst, counts, rank,
                                           W1, W2, W3, Wd1, Wd2,
                                           P1, P2, P3, Pd1, Pd2, epay);
    scan1_kernel<<<gN, blk, 0, stream>>>(counts, eblk, bsum, dinv);
    scan2_kernel<<<1, blk, 0, stream>>>(bsum, bo, rowptr);
    scan3_kernel<<<gN, blk, 0, stream>>>(eblk, bo, rowptr);
    csr_fill_kernel<<<gE, blk, 0, stream>>>(src, dst, dinv, rowptr, rank, epay);

    // ---- layer 1..3 ----
    fused_layer_kernel<false><<<gFused, blk, 0, stream>>>(
        rowptr, epay, dinv, xb, P1, b1, nullptr, nullptr, nullptr, nullptr, bufA, nullptr);
    fused_layer_kernel<false><<<gFused, blk, 0, stream>>>(
        rowptr, epay, dinv, bufA, P2, b2, nullptr, nullptr, nullptr, nullptr, bufB, nullptr);
    fused_layer_kernel<true><<<gFused, blk, 0, stream>>>(
        rowptr, epay, dinv, bufB, P3, b3, Pd1, bd1, Pd2, bd2, nullptr, (float*)d_out);
}

// Round 11
// 254.564 us; speedup vs baseline: 19.9026x; 1.0163x over previous
//
#include <hip/hip_runtime.h>
#include <hip/hip_bf16.h>
#include <hip/hip_fp16.h>

#define N_NODES 50000
#define N_EDGES 800000
#define C_H 128
#define C_OUT 64
#define NBLK 196          // ceil(50000/256)
#define TSTRIDE 136       // LDS tile row stride in bf16
#define E_PAD 950272      // >= N_EDGES + 3*N_NODES, 1024-aligned
#define MM_BLKS 782       // ceil(50000/64) row-tiles for the XW1 matmul

typedef __attribute__((ext_vector_type(8))) short bf16x8;
typedef __attribute__((ext_vector_type(4))) float f32x4;

static __device__ __forceinline__ float bf_lo(unsigned int u) { return __uint_as_float(u << 16); }
static __device__ __forceinline__ float bf_hi(unsigned int u) { return __uint_as_float(u & 0xffff0000u); }
static __device__ __forceinline__ unsigned short f2bf(float f) {
    __hip_bfloat16 h = __float2bfloat16(f);
    return *(unsigned short*)&h;
}
static __device__ __forceinline__ unsigned int pack2(float a, float b) {
    return (unsigned int)f2bf(a) | ((unsigned int)f2bf(b) << 16);
}
static __device__ __forceinline__ unsigned short f2h_bits(float f) {
    union { __half h; unsigned short u; } c; c.h = __float2half_rn(f); return c.u;
}
static __device__ __forceinline__ float h_bits2f(unsigned short u) {
    union { __half h; unsigned short u; } c; c.u = u; return __half2float(c.h);
}

// ================= prep: hist(+rank) + pack W + zero epay =================
// block ranges: [0,3125) hist | [3125,3413) pack | [3413,4341) zero
__global__ void prep_kernel(const int* __restrict__ dst, int* __restrict__ counts,
                            int* __restrict__ rank,
                            const float* __restrict__ W1, const float* __restrict__ W2,
                            const float* __restrict__ W3, const float* __restrict__ Wd1,
                            const float* __restrict__ Wd2,
                            unsigned short* __restrict__ P1, unsigned short* __restrict__ P2,
                            unsigned short* __restrict__ P3, unsigned short* __restrict__ Pd1,
                            unsigned short* __restrict__ Pd2,
                            unsigned int* __restrict__ epay) {
    int b = blockIdx.x;
    if (b < 3125) {                               // hist over edges, capture rank
        int e = b * 256 + threadIdx.x;
        rank[e] = atomicAdd(&counts[dst[e]], 1);
    } else if (b < 3413) {                        // pack weights
        int idx = (b - 3125) * 256 + threadIdx.x;
        if (idx < 4 * 16384) {
            int which = idx >> 14;
            int r = idx & 16383;
            const float* W = (which == 0) ? W1 : (which == 1) ? W2 : (which == 2) ? W3 : Wd1;
            unsigned short* P = (which == 0) ? P1 : (which == 1) ? P2 : (which == 2) ? P3 : Pd1;
            int j = r & 7, lane = (r >> 3) & 63, t = r >> 9;
            int nb = t & 7, kb = t >> 3;          // NB=8
            int k = kb * 32 + ((lane >> 4) << 3) + j;
            int n = nb * 16 + (lane & 15);
            P[r] = f2bf(W[(size_t)k * 128 + n]);
        } else {
            int r = idx - 65536;
            if (r < 8192) {
                int j = r & 7, lane = (r >> 3) & 63, t = r >> 9;
                int nb = t & 3, kb = t >> 2;      // NB=4
                int k = kb * 32 + ((lane >> 4) << 3) + j;
                int n = nb * 16 + (lane & 15);
                Pd2[r] = f2bf(Wd2[(size_t)k * 64 + n]);
            }
        }
    } else {                                      // zero epay: 928 blocks x 1024 uints
        int i = (b - 3413) * 256 + threadIdx.x;
        *(uint4*)(epay + (size_t)i * 4) = make_uint4(0, 0, 0, 0);
    }
}

// ================= CSR scans (degree padded to multiple of 4) =================
__global__ void __launch_bounds__(256) scan1_kernel(const int* __restrict__ counts,
                                                    int* __restrict__ eblk,
                                                    int* __restrict__ bsum,
                                                    float* __restrict__ dinv) {
    __shared__ int ws[4];
    int i = blockIdx.x * 256 + threadIdx.x;
    int v = (i < N_NODES) ? counts[i] : 0;
    if (i < N_NODES) dinv[i] = rsqrtf((float)v + 1.0f);
    int vp = (v + 3) & ~3;                        // padded degree
    int lane = threadIdx.x & 63, w = threadIdx.x >> 6;
    int x = vp;
    #pragma unroll
    for (int off = 1; off < 64; off <<= 1) {
        int t = __shfl_up(x, off, 64);
        if (lane >= off) x += t;
    }
    if (lane == 63) ws[w] = x;
    __syncthreads();
    if (threadIdx.x == 0) {
        int run = 0;
        #pragma unroll
        for (int k = 0; k < 4; ++k) { int t = ws[k]; ws[k] = run; run += t; }
        bsum[blockIdx.x] = run;
    }
    __syncthreads();
    if (i < N_NODES) eblk[i] = x - vp + ws[w];
}

__global__ void __launch_bounds__(256) scan2_kernel(const int* __restrict__ bsum,
                                                    int* __restrict__ bo,
                                                    int* __restrict__ rowptr) {
    __shared__ int ws[4];
    int i = threadIdx.x;
    int v = (i < NBLK) ? bsum[i] : 0;
    int lane = i & 63, w = i >> 6;
    int x = v;
    #pragma unroll
    for (int off = 1; off < 64; off <<= 1) {
        int t = __shfl_up(x, off, 64);
        if (lane >= off) x += t;
    }
    if (lane == 63) ws[w] = x;
    __syncthreads();
    if (i == 0) {
        int run = 0;
        #pragma unroll
        for (int k = 0; k < 4; ++k) { int t = ws[k]; ws[k] = run; run += t; }
    }
    __syncthreads();
    int excl = x - v + ws[w];
    if (i < NBLK) bo[i] = excl;
    if (i == 255) rowptr[N_NODES] = excl + v;
}

__global__ void scan3_kernel(const int* __restrict__ eblk, const int* __restrict__ bo,
                             int* __restrict__ rowptr) {
    int i = blockIdx.x * 256 + threadIdx.x;
    if (i < N_NODES) rowptr[i] = eblk[i] + bo[blockIdx.x];
}

// ================= heterogeneous: XW1 matmul + csr fill =================
// blocks [0, MM_BLKS): XW1 = x(fp32) @ P1 -> bf16 (no bias; fill's idle slots hide it)
// blocks [MM_BLKS, MM_BLKS+3125): epay[rowptr[d]+rank[e]] = {u16 src, f16 norm}
__global__ void __launch_bounds__(256) fill_mm_kernel(
        const float* __restrict__ x, const unsigned short* __restrict__ P1,
        unsigned short* __restrict__ XW1,
        const int* __restrict__ src, const int* __restrict__ dst,
        const float* __restrict__ dinv,
        const int* __restrict__ rowptr, const int* __restrict__ rank,
        unsigned int* __restrict__ epay) {
    int b = blockIdx.x;
    if (b < MM_BLKS) {
        const int lane = threadIdx.x & 63;
        const int wave = threadIdx.x >> 6;
        const int wid  = b * 4 + wave;
        if (wid * 16 >= N_NODES) return;          // exact: 3125 waves used
        const int node = wid * 16 + (lane & 15);
        const int quad = lane >> 4;
        f32x4 acc[8];
        #pragma unroll
        for (int nb = 0; nb < 8; ++nb) acc[nb] = (f32x4){0.f, 0.f, 0.f, 0.f};
        #pragma unroll
        for (int kb = 0; kb < 4; ++kb) {
            const float* p = x + (size_t)node * 128 + kb * 32 + quad * 8;
            float4 lo = *(const float4*)p;
            float4 hi = *(const float4*)(p + 4);
            union { bf16x8 v; unsigned int u[4]; } tmp;
            tmp.u[0] = pack2(lo.x, lo.y); tmp.u[1] = pack2(lo.z, lo.w);
            tmp.u[2] = pack2(hi.x, hi.y); tmp.u[3] = pack2(hi.z, hi.w);
            #pragma unroll
            for (int nb = 0; nb < 8; ++nb) {
                bf16x8 wf = *(const bf16x8*)(P1 + ((size_t)(kb * 8 + nb) * 64 + lane) * 8);
                acc[nb] = __builtin_amdgcn_mfma_f32_16x16x32_bf16(wf, tmp.v, acc[nb], 0, 0, 0);
            }
        }
        #pragma unroll
        for (int nb = 0; nb < 8; ++nb) {
            int ch = nb * 16 + quad * 4;
            uint2 o;
            o.x = pack2(acc[nb][0], acc[nb][1]);
            o.y = pack2(acc[nb][2], acc[nb][3]);
            *(uint2*)(XW1 + (size_t)node * C_H + ch) = o;
        }
    } else {
        int e = (b - MM_BLKS) * 256 + threadIdx.x;
        if (e < N_EDGES) {
            int d = dst[e], s = src[e];
            int pos = rowptr[d] + rank[e];
            float nrm = dinv[s] * dinv[d];
            epay[pos] = (unsigned int)s | ((unsigned int)f2h_bits(nrm) << 16);
        }
    }
}

// ================= layer 1: pure gather(XW1) + bias + relu -> bf16 =================
__global__ void __launch_bounds__(256) gather1_kernel(
        const int* __restrict__ rowptr,
        const unsigned int* __restrict__ epay,
        const float* __restrict__ dinv,
        const unsigned short* __restrict__ hin,
        const float* __restrict__ bias,
        unsigned short* __restrict__ out) {
    int t    = blockIdx.x * 256 + threadIdx.x;
    int node = t >> 4;
    int c8   = (t & 15) << 3;

    float di = dinv[node], dii = di * di;
    uint4 raw = *(const uint4*)(hin + (size_t)node * C_H + c8);
    float a0 = bf_lo(raw.x) * dii, a1 = bf_hi(raw.x) * dii;
    float a2 = bf_lo(raw.y) * dii, a3 = bf_hi(raw.y) * dii;
    float a4 = bf_lo(raw.z) * dii, a5 = bf_hi(raw.z) * dii;
    float a6 = bf_lo(raw.w) * dii, a7 = bf_hi(raw.w) * dii;
    int beg = rowptr[node], end = rowptr[node + 1];
    int p = beg;
    for (; p + 8 <= end; p += 8) {
        uint4 ev0 = *(const uint4*)(epay + p);
        uint4 ev1 = *(const uint4*)(epay + p + 4);
        unsigned int ee[8] = {ev0.x, ev0.y, ev0.z, ev0.w, ev1.x, ev1.y, ev1.z, ev1.w};
        uint4 rv[8];
        #pragma unroll
        for (int j = 0; j < 8; ++j)
            rv[j] = *(const uint4*)(hin + (size_t)(ee[j] & 0xffffu) * C_H + c8);
        #pragma unroll
        for (int j = 0; j < 8; ++j) {
            float nm = h_bits2f((unsigned short)(ee[j] >> 16));
            a0 = fmaf(bf_lo(rv[j].x), nm, a0); a1 = fmaf(bf_hi(rv[j].x), nm, a1);
            a2 = fmaf(bf_lo(rv[j].y), nm, a2); a3 = fmaf(bf_hi(rv[j].y), nm, a3);
            a4 = fmaf(bf_lo(rv[j].z), nm, a4); a5 = fmaf(bf_hi(rv[j].z), nm, a5);
            a6 = fmaf(bf_lo(rv[j].w), nm, a6); a7 = fmaf(bf_hi(rv[j].w), nm, a7);
        }
    }
    if (p < end) {
        uint4 ev = *(const uint4*)(epay + p);
        unsigned int ee[4] = {ev.x, ev.y, ev.z, ev.w};
        uint4 rv[4];
        #pragma unroll
        for (int j = 0; j < 4; ++j)
            rv[j] = *(const uint4*)(hin + (size_t)(ee[j] & 0xffffu) * C_H + c8);
        #pragma unroll
        for (int j = 0; j < 4; ++j) {
            float nm = h_bits2f((unsigned short)(ee[j] >> 16));
            a0 = fmaf(bf_lo(rv[j].x), nm, a0); a1 = fmaf(bf_hi(rv[j].x), nm, a1);
            a2 = fmaf(bf_lo(rv[j].y), nm, a2); a3 = fmaf(bf_hi(rv[j].y), nm, a3);
            a4 = fmaf(bf_lo(rv[j].z), nm, a4); a5 = fmaf(bf_hi(rv[j].z), nm, a5);
            a6 = fmaf(bf_lo(rv[j].w), nm, a6); a7 = fmaf(bf_hi(rv[j].w), nm, a7);
        }
    }
    float4 ba = *(const float4*)(bias + c8);
    float4 bb = *(const float4*)(bias + c8 + 4);
    a0 = fmaxf(a0 + ba.x, 0.f); a1 = fmaxf(a1 + ba.y, 0.f);
    a2 = fmaxf(a2 + ba.z, 0.f); a3 = fmaxf(a3 + ba.w, 0.f);
    a4 = fmaxf(a4 + bb.x, 0.f); a5 = fmaxf(a5 + bb.y, 0.f);
    a6 = fmaxf(a6 + bb.z, 0.f); a7 = fmaxf(a7 + bb.w, 0.f);
    uint4 o;
    o.x = pack2(a0, a1); o.y = pack2(a2, a3);
    o.z = pack2(a4, a5); o.w = pack2(a6, a7);
    *(uint4*)(out + (size_t)node * C_H + c8) = o;
}

// ================= fused layer: gather(A·H) -> LDS tile -> MFMA chain =================
template <bool FINAL>
__global__ void __launch_bounds__(256) fused_layer_kernel(
        const int* __restrict__ rowptr,
        const unsigned int* __restrict__ epay,
        const float* __restrict__ dinv,
        const unsigned short* __restrict__ hin,
        const unsigned short* __restrict__ Wp,
        const float* __restrict__ bias,
        const unsigned short* __restrict__ Wd1p,
        const float* __restrict__ bd1,
        const unsigned short* __restrict__ Wd2p,
        const float* __restrict__ bd2,
        unsigned short* __restrict__ out_b,
        float* __restrict__ out_f) {
    __shared__ unsigned short sG[16 * TSTRIDE];
    const int t = threadIdx.x;

    // ---- phase A: gather agg row into LDS tile, 8 edges in flight ----
    {
        int nl = t >> 4, c8 = (t & 15) << 3;
        int node = blockIdx.x * 16 + nl;
        float di = dinv[node], dii = di * di;
        uint4 raw = *(const uint4*)(hin + (size_t)node * C_H + c8);
        float a0 = bf_lo(raw.x) * dii, a1 = bf_hi(raw.x) * dii;
        float a2 = bf_lo(raw.y) * dii, a3 = bf_hi(raw.y) * dii;
        float a4 = bf_lo(raw.z) * dii, a5 = bf_hi(raw.z) * dii;
        float a6 = bf_lo(raw.w) * dii, a7 = bf_hi(raw.w) * dii;
        int beg = rowptr[node], end = rowptr[node + 1];
        int p = beg;
        for (; p + 8 <= end; p += 8) {
            uint4 ev0 = *(const uint4*)(epay + p);
            uint4 ev1 = *(const uint4*)(epay + p + 4);
            unsigned int ee[8] = {ev0.x, ev0.y, ev0.z, ev0.w, ev1.x, ev1.y, ev1.z, ev1.w};
            uint4 rv[8];
            #pragma unroll
            for (int j = 0; j < 8; ++j)
                rv[j] = *(const uint4*)(hin + (size_t)(ee[j] & 0xffffu) * C_H + c8);
            #pragma unroll
            for (int j = 0; j < 8; ++j) {
                float nm = h_bits2f((unsigned short)(ee[j] >> 16));
                a0 = fmaf(bf_lo(rv[j].x), nm, a0); a1 = fmaf(bf_hi(rv[j].x), nm, a1);
                a2 = fmaf(bf_lo(rv[j].y), nm, a2); a3 = fmaf(bf_hi(rv[j].y), nm, a3);
                a4 = fmaf(bf_lo(rv[j].z), nm, a4); a5 = fmaf(bf_hi(rv[j].z), nm, a5);
                a6 = fmaf(bf_lo(rv[j].w), nm, a6); a7 = fmaf(bf_hi(rv[j].w), nm, a7);
            }
        }
        if (p < end) {
            uint4 ev = *(const uint4*)(epay + p);
            unsigned int ee[4] = {ev.x, ev.y, ev.z, ev.w};
            uint4 rv[4];
            #pragma unroll
            for (int j = 0; j < 4; ++j)
                rv[j] = *(const uint4*)(hin + (size_t)(ee[j] & 0xffffu) * C_H + c8);
            #pragma unroll
            for (int j = 0; j < 4; ++j) {
                float nm = h_bits2f((unsigned short)(ee[j] >> 16));
                a0 = fmaf(bf_lo(rv[j].x), nm, a0); a1 = fmaf(bf_hi(rv[j].x), nm, a1);
                a2 = fmaf(bf_lo(rv[j].y), nm, a2); a3 = fmaf(bf_hi(rv[j].y), nm, a3);
                a4 = fmaf(bf_lo(rv[j].z), nm, a4); a5 = fmaf(bf_hi(rv[j].z), nm, a5);
                a6 = fmaf(bf_lo(rv[j].w), nm, a6); a7 = fmaf(bf_hi(rv[j].w), nm, a7);
            }
        }
        uint4 o;
        o.x = pack2(a0, a1); o.y = pack2(a2, a3);
        o.z = pack2(a4, a5); o.w = pack2(a6, a7);
        *(uint4*)(sG + nl * TSTRIDE + c8) = o;
    }
    __syncthreads();

    const int lane = t & 63, wave = t >> 6, quad = lane >> 4, row = lane & 15;
    const int node = blockIdx.x * 16 + row;

    // ---- mm1: tile @ Wp (COUT=128), bias+relu ----
    f32x4 acc0 = (f32x4){0.f, 0.f, 0.f, 0.f};
    f32x4 acc1 = (f32x4){0.f, 0.f, 0.f, 0.f};
    const int nb0 = 2 * wave, nb1 = 2 * wave + 1;
    #pragma unroll
    for (int kb = 0; kb < 4; ++kb) {
        bf16x8 hf = *(const bf16x8*)(sG + row * TSTRIDE + kb * 32 + quad * 8);
        bf16x8 wf0 = *(const bf16x8*)(Wp + ((size_t)(kb * 8 + nb0) * 64 + lane) * 8);
        bf16x8 wf1 = *(const bf16x8*)(Wp + ((size_t)(kb * 8 + nb1) * 64 + lane) * 8);
        acc0 = __builtin_amdgcn_mfma_f32_16x16x32_bf16(wf0, hf, acc0, 0, 0, 0);
        acc1 = __builtin_amdgcn_mfma_f32_16x16x32_bf16(wf1, hf, acc1, 0, 0, 0);
    }
    float4 ba0 = *(const float4*)(bias + nb0 * 16 + quad * 4);
    float4 ba1 = *(const float4*)(bias + nb1 * 16 + quad * 4);
    float v00 = fmaxf(acc0[0] + ba0.x, 0.f), v01 = fmaxf(acc0[1] + ba0.y, 0.f);
    float v02 = fmaxf(acc0[2] + ba0.z, 0.f), v03 = fmaxf(acc0[3] + ba0.w, 0.f);
    float v10 = fmaxf(acc1[0] + ba1.x, 0.f), v11 = fmaxf(acc1[1] + ba1.y, 0.f);
    float v12 = fmaxf(acc1[2] + ba1.z, 0.f), v13 = fmaxf(acc1[3] + ba1.w, 0.f);

    if (!FINAL) {
        uint2 o0, o1;
        o0.x = pack2(v00, v01); o0.y = pack2(v02, v03);
        o1.x = pack2(v10, v11); o1.y = pack2(v12, v13);
        *(uint2*)(out_b + (size_t)node * C_H + nb0 * 16 + quad * 4) = o0;
        *(uint2*)(out_b + (size_t)node * C_H + nb1 * 16 + quad * 4) = o1;
        return;
    }

    // ---- FINAL: H3 -> tile -> Wd1 -> tile -> Wd2 -> sigmoid -> out_f ----
    __syncthreads();
    {
        uint2 o0, o1;
        o0.x = pack2(v00, v01); o0.y = pack2(v02, v03);
        o1.x = pack2(v10, v11); o1.y = pack2(v12, v13);
        *(uint2*)(sG + row * TSTRIDE + nb0 * 16 + quad * 4) = o0;
        *(uint2*)(sG + row * TSTRIDE + nb1 * 16 + quad * 4) = o1;
    }
    __syncthreads();

    acc0 = (f32x4){0.f, 0.f, 0.f, 0.f};
    acc1 = (f32x4){0.f, 0.f, 0.f, 0.f};
    #pragma unroll
    for (int kb = 0; kb < 4; ++kb) {
        bf16x8 hf = *(const bf16x8*)(sG + row * TSTRIDE + kb * 32 + quad * 8);
        bf16x8 wf0 = *(const bf16x8*)(Wd1p + ((size_t)(kb * 8 + nb0) * 64 + lane) * 8);
        bf16x8 wf1 = *(const bf16x8*)(Wd1p + ((size_t)(kb * 8 + nb1) * 64 + lane) * 8);
        acc0 = __builtin_amdgcn_mfma_f32_16x16x32_bf16(wf0, hf, acc0, 0, 0, 0);
        acc1 = __builtin_amdgcn_mfma_f32_16x16x32_bf16(wf1, hf, acc1, 0, 0, 0);
    }
    ba0 = *(const float4*)(bd1 + nb0 * 16 + quad * 4);
    ba1 = *(const float4*)(bd1 + nb1 * 16 + quad * 4);
    v00 = fmaxf(acc0[0] + ba0.x, 0.f); v01 = fmaxf(acc0[1] + ba0.y, 0.f);
    v02 = fmaxf(acc0[2] + ba0.z, 0.f); v03 = fmaxf(acc0[3] + ba0.w, 0.f);
    v10 = fmaxf(acc1[0] + ba1.x, 0.f); v11 = fmaxf(acc1[1] + ba1.y, 0.f);
    v12 = fmaxf(acc1[2] + ba1.z, 0.f); v13 = fmaxf(acc1[3] + ba1.w, 0.f);
    __syncthreads();
    {
        uint2 o0, o1;
        o0.x = pack2(v00, v01); o0.y = pack2(v02, v03);
        o1.x = pack2(v10, v11); o1.y = pack2(v12, v13);
        *(uint2*)(sG + row * TSTRIDE + nb0 * 16 + quad * 4) = o0;
        *(uint2*)(sG + row * TSTRIDE + nb1 * 16 + quad * 4) = o1;
    }
    __syncthreads();

    f32x4 acc = (f32x4){0.f, 0.f, 0.f, 0.f};
    #pragma unroll
    for (int kb = 0; kb < 4; ++kb) {
        bf16x8 hf = *(const bf16x8*)(sG + row * TSTRIDE + kb * 32 + quad * 8);
        bf16x8 wf = *(const bf16x8*)(Wd2p + ((size_t)(kb * 4 + wave) * 64 + lane) * 8);
        acc = __builtin_amdgcn_mfma_f32_16x16x32_bf16(wf, hf, acc, 0, 0, 0);
    }
    int ch = wave * 16 + quad * 4;
    float4 b4 = *(const float4*)(bd2 + ch);
    float4 r;
    r.x = 1.f / (1.f + expf(-(acc[0] + b4.x)));
    r.y = 1.f / (1.f + expf(-(acc[1] + b4.y)));
    r.z = 1.f / (1.f + expf(-(acc[2] + b4.z)));
    r.w = 1.f / (1.f + expf(-(acc[3] + b4.w)));
    *(float4*)(out_f + (size_t)node * C_OUT + ch) = r;
}

extern "C" void kernel_launch(void* const* d_in, const int* in_sizes, int n_in,
                              void* d_out, int out_size, void* d_ws, size_t ws_size,
                              hipStream_t stream) {
    const float* x   = (const float*)d_in[0];
    const int*   ei  = (const int*)d_in[1];
    const float* W1  = (const float*)d_in[2];
    const float* b1  = (const float*)d_in[3];
    const float* W2  = (const float*)d_in[4];
    const float* b2  = (const float*)d_in[5];
    const float* W3  = (const float*)d_in[6];
    const float* b3  = (const float*)d_in[7];
    const float* Wd1 = (const float*)d_in[8];
    const float* bd1 = (const float*)d_in[9];
    const float* Wd2 = (const float*)d_in[10];
    const float* bd2 = (const float*)d_in[11];

    const int* src = ei;
    const int* dst = ei + N_EDGES;

    char* base = (char*)d_ws;
    size_t off = 0;
    auto alloc = [&](size_t bytes) { char* p = base + off; off += (bytes + 255) & ~size_t(255); return p; };
    int*            counts = (int*)alloc(50176 * 4);
    unsigned int*   epay   = (unsigned int*)alloc((size_t)E_PAD * 4);
    int*            rank   = (int*)alloc((size_t)N_EDGES * 4);
    float*          dinv   = (float*)alloc(N_NODES * 4);
    int*            rowptr = (int*)alloc((N_NODES + 1) * 4);
    int*            eblk   = (int*)alloc(N_NODES * 4);
    int*            bsum   = (int*)alloc(256 * 4);
    int*            bo     = (int*)alloc(256 * 4);
    unsigned short* XW1    = (unsigned short*)alloc((size_t)N_NODES * C_H * 2);
    unsigned short* bufA   = (unsigned short*)alloc((size_t)N_NODES * C_H * 2);
    unsigned short* bufB   = (unsigned short*)alloc((size_t)N_NODES * C_H * 2);
    unsigned short* P1     = (unsigned short*)alloc(128 * 128 * 2);
    unsigned short* P2     = (unsigned short*)alloc(128 * 128 * 2);
    unsigned short* P3     = (unsigned short*)alloc(128 * 128 * 2);
    unsigned short* Pd1    = (unsigned short*)alloc(128 * 128 * 2);
    unsigned short* Pd2    = (unsigned short*)alloc(128 * 64 * 2);

    const int T = 256;
    dim3 blk(T);
    dim3 gN((N_NODES + T - 1) / T);            // 196
    dim3 gPrep(3125 + 288 + 928);              // hist + pack + zero
    dim3 gFillMM(MM_BLKS + 3125);              // mm + fill
    dim3 gFused(N_NODES / 16);                 // 3125, exact

    hipMemsetAsync(counts, 0, 50176 * 4, stream);
    prep_kernel<<<gPrep, blk, 0, stream>>>(dst, counts, rank,
                                           W1, W2, W3, Wd1, Wd2,
                                           P1, P2, P3, Pd1, Pd2, epay);
    scan1_kernel<<<gN, blk, 0, stream>>>(counts, eblk, bsum, dinv);
    scan2_kernel<<<1, blk, 0, stream>>>(bsum, bo, rowptr);
    scan3_kernel<<<gN, blk, 0, stream>>>(eblk, bo, rowptr);
    fill_mm_kernel<<<gFillMM, blk, 0, stream>>>(x, P1, XW1, src, dst, dinv,
                                                rowptr, rank, epay);

    // ---- layer 1: relu(agg(XW1) + b1) -> bufA (pure gather) ----
    gather1_kernel<<<gFused, blk, 0, stream>>>(rowptr, epay, dinv, XW1, b1, bufA);
    // ---- layer 2 ----
    fused_layer_kernel<false><<<gFused, blk, 0, stream>>>(
        rowptr, epay, dinv, bufA, P2, b2, nullptr, nullptr, nullptr, nullptr, bufB, nullptr);
    // ---- layer 3 + dense head ----
    fused_layer_kernel<true><<<gFused, blk, 0, stream>>>(
        rowptr, epay, dinv, bufB, P3, b3, Pd1, bd1, Pd2, bd2, nullptr, (float*)d_out);
}